// Round 18
// baseline (154.773 us; speedup 1.0000x reference)
//
#include <hip/hip_runtime.h>
#include <hip/hip_bf16.h>

typedef short v8s __attribute__((ext_vector_type(8)));
typedef unsigned short v8u __attribute__((ext_vector_type(8)));
typedef float v4f __attribute__((ext_vector_type(4)));
typedef unsigned short u16;

#define LL 1024
#define DD 1024

static __device__ __forceinline__ u16 f2b(float x) {
  __hip_bfloat16 h = __float2bfloat16(x);
  return __builtin_bit_cast(u16, h);
}
static __device__ __forceinline__ float b2f(u16 u) {
  unsigned int x = ((unsigned int)u) << 16;
  return __builtin_bit_cast(float, x);
}

static __device__ __forceinline__ void gload_lds16(const u16* g, u16* l) {
  __builtin_amdgcn_global_load_lds((const __attribute__((address_space(1))) void*)g,
                                   (__attribute__((address_space(3))) void*)l, 16, 0, 0);
}

// ---------------- f32 -> bf16 conversion, 4 weight tensors only --------------
// (Q/K/V conversion is fused into gemm_proj's A-staging.)
__global__ __launch_bounds__(256) void cvt4(const float* __restrict__ p0,
                                            const float* __restrict__ p1,
                                            const float* __restrict__ p2,
                                            const float* __restrict__ p3,
                                            u16* __restrict__ dst0) {
  const long NK = 1024L * 1024;
  const int y = blockIdx.y;
  const float* srcs[4] = {p0, p1, p2, p3};
  const float* src = srcs[y];
  u16* dst = dst0 + (long)y * NK;
  int i = blockIdx.x * 256 + threadIdx.x;
  const float4* p = (const float4*)src + (long)i * 2;
  float4 a = p[0], b = p[1];
  v8u r;
  r[0] = f2b(a.x); r[1] = f2b(a.y); r[2] = f2b(a.z); r[3] = f2b(a.w);
  r[4] = f2b(b.x); r[5] = f2b(b.y); r[6] = f2b(b.z); r[7] = f2b(b.w);
  *((v8u*)dst + i) = r;
}

// ---------------- per-head counting sort of q-rows by effective valid len ----
__global__ __launch_bounds__(256) void sortperm(const int* __restrict__ valid,
                                                u16* __restrict__ perm) {
  __shared__ int hist[1024];
  __shared__ int wsum[4];
  const int bh = blockIdx.x;
  const int tid = threadIdx.x;
  const int* v = valid + bh * 1024;
  for (int i = tid; i < 1024; i += 256) hist[i] = 0;
  __syncthreads();
  for (int i = tid; i < 1024; i += 256) {
    int k = v[i];
    k = (k == 0) ? 1023 : (k - 1);  // bin = eff-1
    atomicAdd(&hist[k], 1);
  }
  __syncthreads();
  const int base = tid * 4;
  int h0 = hist[base], h1 = hist[base + 1], h2 = hist[base + 2], h3 = hist[base + 3];
  int local = h0 + h1 + h2 + h3;
  const int lane = tid & 63, w = tid >> 6;
  int scan = local;
#pragma unroll
  for (int d = 1; d < 64; d <<= 1) {
    int t = __shfl_up(scan, d);
    if (lane >= d) scan += t;
  }
  if (lane == 63) wsum[w] = scan;
  __syncthreads();
  int woff = 0;
  for (int i = 0; i < w; ++i) woff += wsum[i];
  int excl = woff + scan - local;
  hist[base] = excl;
  hist[base + 1] = excl + h0;
  hist[base + 2] = excl + h0 + h1;
  hist[base + 3] = excl + h0 + h1 + h2;
  __syncthreads();
  for (int i = tid; i < 1024; i += 256) {
    int k = v[i];
    k = (k == 0) ? 1023 : (k - 1);
    int pos = atomicAdd(&hist[k], 1);
    perm[bh * 1024 + pos] = (u16)i;
  }
}

// ---------------- proj GEMM: C = A_f32 * W_bf16^T, A converted in-staging -----
// 128x128 tile, BK=64. B staged via global_load_lds (issued FIRST, async);
// A reg-staged from f32 + cvt to bf16 + ds_write (same linear LDS layout;
// identical RNE rounding as the old cvt pass -> bitwise-identical output).
__global__ __launch_bounds__(256) void gemm_proj(const float* __restrict__ Qf,
                                                 const float* __restrict__ Kf,
                                                 const float* __restrict__ Vf,
                                                 const u16* __restrict__ Bw,
                                                 u16* __restrict__ C) {
  __shared__ u16 As[128 * 64];
  __shared__ u16 Bs[128 * 64];
  const float* A = blockIdx.z == 0 ? Qf : (blockIdx.z == 1 ? Kf : Vf);
  const u16* Bz = Bw + (long)blockIdx.z * 1024 * 1024;
  u16* Cz = C + (long)blockIdx.z * 4096 * 1024;
  const int tid = threadIdx.x;
  const int lane = tid & 63;
  const int l15 = lane & 15, lg = lane >> 4;
  const int wid = tid >> 6;
  const int wm = wid >> 1, wn = wid & 1;
  const long mbase = (long)blockIdx.y * 128;
  const long nbase = (long)blockIdx.x * 128;

  const float* ap = A + (mbase + (tid >> 3)) * 1024 + (tid & 7) * 8;
  const u16* bp = Bz + (nbase + (tid >> 3)) * 1024 + (tid & 7) * 8;

  v4f acc[4][4] = {};

  for (int kt = 0; kt < 16; ++kt) {
    __syncthreads();
    // B first: async global->LDS transfers overlap A's load+convert below
#pragma unroll
    for (int j = 0; j < 4; ++j)
      gload_lds16(bp + kt * 64 + j * 32 * 1024, &Bs[(tid + 256 * j) * 8]);
    // A: f32 load -> bf16 convert -> ds_write (fused cvt)
#pragma unroll
    for (int j = 0; j < 4; ++j) {
      const float* s = ap + kt * 64 + (long)j * 32 * 1024;
      float4 x = *(const float4*)s;
      float4 y = *(const float4*)(s + 4);
      v8u r;
      r[0] = f2b(x.x); r[1] = f2b(x.y); r[2] = f2b(x.z); r[3] = f2b(x.w);
      r[4] = f2b(y.x); r[5] = f2b(y.y); r[6] = f2b(y.z); r[7] = f2b(y.w);
      *(v8u*)&As[(tid + 256 * j) * 8] = r;
    }
    __syncthreads();  // drains vmcnt (B in LDS) + lgkm (A writes visible)
#pragma unroll
    for (int kk = 0; kk < 2; ++kk) {
      v8s a[4], b[4];
#pragma unroll
      for (int i = 0; i < 4; ++i)
        a[i] = *(const v8s*)&As[(wm * 64 + i * 16 + l15) * 64 + kk * 32 + lg * 8];
#pragma unroll
      for (int i = 0; i < 4; ++i)
        b[i] = *(const v8s*)&Bs[(wn * 64 + i * 16 + l15) * 64 + kk * 32 + lg * 8];
#pragma unroll
      for (int mi = 0; mi < 4; ++mi)
#pragma unroll
        for (int nj = 0; nj < 4; ++nj)
          acc[mi][nj] = __builtin_amdgcn_mfma_f32_16x16x32_bf16(a[mi], b[nj], acc[mi][nj], 0, 0, 0);
    }
  }
#pragma unroll
  for (int mi = 0; mi < 4; ++mi) {
#pragma unroll
    for (int r = 0; r < 4; ++r) {
      long row = mbase + wm * 64 + mi * 16 + lg * 4 + r;
#pragma unroll
      for (int nj = 0; nj < 4; ++nj) {
        long col = nbase + wn * 64 + nj * 16 + l15;
        Cz[row * 1024 + col] = f2b(acc[mi][nj][r]);
      }
    }
  }
}

// ---------------- C[M,N] = A[M,K] * B[N,K]^T, 64x128 tile (out GEMM) ----------
// 512 blocks = 2/CU -> inter-block overlap hides barrier-drain stalls.
__global__ __launch_bounds__(256) void gemm_bt64(const u16* __restrict__ A,
                                                 const u16* __restrict__ Bw,
                                                 float* __restrict__ C) {
  __shared__ u16 As[64 * 64];
  __shared__ u16 Bs[128 * 64];
  const int tid = threadIdx.x;
  const int lane = tid & 63;
  const int l15 = lane & 15, lg = lane >> 4;
  const int wid = tid >> 6;
  const int wm = wid >> 1, wn = wid & 1;  // wave = 32 rows x 64 cols
  const long mbase = (long)blockIdx.y * 64;
  const long nbase = (long)blockIdx.x * 128;

  const u16* ap = A + (mbase + (tid >> 3)) * 1024 + (tid & 7) * 8;
  const u16* bp = Bw + (nbase + (tid >> 3)) * 1024 + (tid & 7) * 8;

  v4f acc[2][4] = {};

  for (int kt = 0; kt < 16; ++kt) {
    __syncthreads();
#pragma unroll
    for (int j = 0; j < 2; ++j)
      gload_lds16(ap + kt * 64 + j * 32 * 1024, &As[(tid + 256 * j) * 8]);
#pragma unroll
    for (int j = 0; j < 4; ++j)
      gload_lds16(bp + kt * 64 + j * 32 * 1024, &Bs[(tid + 256 * j) * 8]);
    __syncthreads();
#pragma unroll
    for (int kk = 0; kk < 2; ++kk) {
      v8s a[2], b[4];
#pragma unroll
      for (int i = 0; i < 2; ++i)
        a[i] = *(const v8s*)&As[(wm * 32 + i * 16 + l15) * 64 + kk * 32 + lg * 8];
#pragma unroll
      for (int i = 0; i < 4; ++i)
        b[i] = *(const v8s*)&Bs[(wn * 64 + i * 16 + l15) * 64 + kk * 32 + lg * 8];
#pragma unroll
      for (int mi = 0; mi < 2; ++mi)
#pragma unroll
        for (int nj = 0; nj < 4; ++nj)
          acc[mi][nj] = __builtin_amdgcn_mfma_f32_16x16x32_bf16(a[mi], b[nj], acc[mi][nj], 0, 0, 0);
    }
  }
#pragma unroll
  for (int mi = 0; mi < 2; ++mi) {
#pragma unroll
    for (int r = 0; r < 4; ++r) {
      long row = mbase + wm * 32 + mi * 16 + lg * 4 + r;
#pragma unroll
      for (int nj = 0; nj < 4; ++nj) {
        long col = nbase + wn * 64 + nj * 16 + l15;
        C[row * 1024 + col] = acc[mi][nj][r];
      }
    }
  }
}

// ---------------- fused masked attention, split-K x3 (chunk=6 tiles) ----------
__global__ __launch_bounds__(256) void attn_kern(const u16* __restrict__ qb,
                                                 const u16* __restrict__ kb,
                                                 const u16* __restrict__ vb,
                                                 const int* __restrict__ valid,
                                                 const u16* __restrict__ perm,
                                                 u16* __restrict__ partO,
                                                 float* __restrict__ partM,
                                                 float* __restrict__ partL) {
  __shared__ u16 Ks[64 * 72];       // [key][hd], +8 pad -> no 16-way conflict
  __shared__ u16 Vt[64 * 72];       // [hd][key], transposed for PV B-operand
  __shared__ u16 Ps[4][16 * 72];    // per-wave P tile [q][key]

  const int tid = threadIdx.x;
  const int lane = tid & 63;
  const int wid = tid >> 6;
  const int l15 = lane & 15, lg = lane >> 4;
  const int bh = blockIdx.y;
  const int b = bh >> 4, h = bh & 15;
  const long headoff = ((long)b * LL) * DD + h * 64;
  const int xx = blockIdx.x;
  const int gq = 15 - (xx / 3);    // heaviest sorted group dispatched first
  const int ch = xx % 3;
  const u16* pblk = perm + bh * 1024 + gq * 64;

  const int lastv = valid[bh * LL + pblk[63]];
  const int ntiles = ((lastv == 0 ? LL : lastv) + 63) >> 6;
  const int kt0 = ch * 6;
  const int kt1 = min(ntiles, kt0 + 6);
  if (kt0 >= kt1) return;  // chunk absent for lighter groups
  const int slot = (bh * 16 + gq) * 3 + ch;

  const u16* pp = pblk + wid * 16;

  // Q A-fragments (rows via perm) live in registers for the whole kernel
  const int qrowA = pp[l15];
  v8s qf[2];
#pragma unroll
  for (int ks = 0; ks < 2; ++ks)
    qf[ks] = *(const v8s*)(qb + headoff + (long)qrowA * DD + ks * 32 + lg * 8);

  // per-lane C-frag rows (lg*4+r): raw valid for masking
  int vraw[4];
#pragma unroll
  for (int r = 0; r < 4; ++r) vraw[r] = valid[bh * LL + pp[lg * 4 + r]];

  float mrow[4], lrow[4];
  v4f oacc[4] = {};
#pragma unroll
  for (int r = 0; r < 4; ++r) { mrow[r] = -1e30f; lrow[r] = 0.0f; }

  const int kk = tid & 63;   // staging: key row
  const int qtr = tid >> 6;  // staging: 16-wide hd quarter
  const long stagebase = headoff + (long)kk * DD + qtr * 16;

  // prologue: issue first tile's K/V loads (reg staging, write-late)
  v8s rk0 = *(const v8s*)(kb + stagebase + (long)kt0 * 64 * DD);
  v8s rk1 = *(const v8s*)(kb + stagebase + (long)kt0 * 64 * DD + 8);
  v8s rv0 = *(const v8s*)(vb + stagebase + (long)kt0 * 64 * DD);
  v8s rv1 = *(const v8s*)(vb + stagebase + (long)kt0 * 64 * DD + 8);

  for (int kt = kt0; kt < kt1; ++kt) {
    // ---- barrier A (WAR guard): raw s_barrier, no vmcnt drain.
    __builtin_amdgcn_sched_barrier(0);
    __builtin_amdgcn_s_barrier();
    __builtin_amdgcn_sched_barrier(0);

    // commit staged regs -> LDS (compiler inserts COUNTED vmcnt for rk*/rv*)
    *(v8s*)&Ks[kk * 72 + qtr * 16] = rk0;
    *(v8s*)&Ks[kk * 72 + qtr * 16 + 8] = rk1;
    {
      v8u u0 = __builtin_bit_cast(v8u, rv0);
      v8u u1 = __builtin_bit_cast(v8u, rv1);
#pragma unroll
      for (int j = 0; j < 8; ++j) Vt[(qtr * 16 + j) * 72 + kk] = u0[j];
#pragma unroll
      for (int j = 0; j < 8; ++j) Vt[(qtr * 16 + 8 + j) * 72 + kk] = u1[j];
    }
    // prefetch next tile's K/V; stays in flight across barrier B + compute
    if (kt + 1 < kt1) {
      const long noff = stagebase + (long)(kt + 1) * 64 * DD;
      rk0 = *(const v8s*)(kb + noff);
      rk1 = *(const v8s*)(kb + noff + 8);
      rv0 = *(const v8s*)(vb + noff);
      rv1 = *(const v8s*)(vb + noff + 8);
    }
    // ---- barrier B: ds_writes visible; vmcnt NOT drained.
    asm volatile("s_waitcnt lgkmcnt(0)" ::: "memory");
    __builtin_amdgcn_sched_barrier(0);
    __builtin_amdgcn_s_barrier();
    __builtin_amdgcn_sched_barrier(0);

    // S = Q K^T for 16 q rows x 64 keys
    v4f s[4];
    __builtin_amdgcn_s_setprio(1);
#pragma unroll
    for (int t = 0; t < 4; ++t) {
      v4f z = {};
#pragma unroll
      for (int ks = 0; ks < 2; ++ks) {
        v8s kf = *(const v8s*)&Ks[(t * 16 + l15) * 72 + ks * 32 + lg * 8];
        z = __builtin_amdgcn_mfma_f32_16x16x32_bf16(qf[ks], kf, z, 0, 0, 0);
      }
      s[t] = z;
    }
    __builtin_amdgcn_s_setprio(0);

    // scale into log2 domain + mask (ref semantics: -1e6, col < valid_raw)
    const float SC = 0.18033688f;  // (1/8) * log2(e)
    const int colbase = kt * 64 + l15;
#pragma unroll
    for (int t = 0; t < 4; ++t)
#pragma unroll
      for (int r = 0; r < 4; ++r) {
        float val = s[t][r] * SC;
        s[t][r] = (colbase + t * 16 < vraw[r]) ? val : -1e6f;
      }

    // online softmax (log2 domain) with defer-max: rescale only if max grew >11
    float pm[4];
#pragma unroll
    for (int r = 0; r < 4; ++r)
      pm[r] = fmaxf(fmaxf(s[0][r], s[1][r]), fmaxf(s[2][r], s[3][r]));
#pragma unroll
    for (int d = 1; d < 16; d <<= 1)
#pragma unroll
      for (int r = 0; r < 4; ++r) pm[r] = fmaxf(pm[r], __shfl_xor(pm[r], d));

    bool sk = true;
#pragma unroll
    for (int r = 0; r < 4; ++r) sk = sk && (pm[r] <= mrow[r] + 11.0f);
    if (!__all(sk)) {
#pragma unroll
      for (int r = 0; r < 4; ++r) {
        float mn = fmaxf(mrow[r], pm[r]);
        float sc = __builtin_amdgcn_exp2f(mrow[r] - mn);
        mrow[r] = mn;
        lrow[r] *= sc;
#pragma unroll
        for (int t = 0; t < 4; ++t) oacc[t][r] *= sc;
      }
    }
    float rs[4] = {0.f, 0.f, 0.f, 0.f};
#pragma unroll
    for (int t = 0; t < 4; ++t)
#pragma unroll
      for (int r = 0; r < 4; ++r) {
        float p = __builtin_amdgcn_exp2f(s[t][r] - mrow[r]);
        s[t][r] = p;
        rs[r] += p;
      }
#pragma unroll
    for (int d = 1; d < 16; d <<= 1)
#pragma unroll
      for (int r = 0; r < 4; ++r) rs[r] += __shfl_xor(rs[r], d);
#pragma unroll
    for (int r = 0; r < 4; ++r) lrow[r] += rs[r];

    // P -> bf16 -> per-wave LDS, then consume as MFMA A-operand
#pragma unroll
    for (int t = 0; t < 4; ++t)
#pragma unroll
      for (int r = 0; r < 4; ++r)
        Ps[wid][(lg * 4 + r) * 72 + t * 16 + l15] = f2b(s[t][r]);

    asm volatile("s_waitcnt lgkmcnt(0)" ::: "memory");
    __builtin_amdgcn_sched_barrier(0);

    __builtin_amdgcn_s_setprio(1);
#pragma unroll
    for (int ks = 0; ks < 2; ++ks) {
      v8s pa = *(const v8s*)&Ps[wid][l15 * 72 + ks * 32 + lg * 8];
#pragma unroll
      for (int t = 0; t < 4; ++t) {
        v8s vf = *(const v8s*)&Vt[(t * 16 + l15) * 72 + ks * 32 + lg * 8];
        oacc[t] = __builtin_amdgcn_mfma_f32_16x16x32_bf16(pa, vf, oacc[t], 0, 0, 0);
      }
    }
    __builtin_amdgcn_s_setprio(0);
  }

  // epilogue: write UNNORMALIZED partials (sorted-row order); merge normalizes
  u16* po = partO + (long)slot * 4096;
  float* pmv = partM + slot * 64;
  float* plv = partL + slot * 64;
#pragma unroll
  for (int r = 0; r < 4; ++r) {
    int p = wid * 16 + lg * 4 + r;
    pmv[p] = mrow[r];
    plv[p] = lrow[r];
#pragma unroll
    for (int t = 0; t < 4; ++t)
      po[p * 64 + t * 16 + l15] = f2b(oacc[t][r]);
  }
}

// ---------------- merge the (up to 3) chunk partials per (bh, group) ----------
__global__ __launch_bounds__(256) void merge_kern(const int* __restrict__ valid,
                                                  const u16* __restrict__ perm,
                                                  const u16* __restrict__ partO,
                                                  const float* __restrict__ partM,
                                                  const float* __restrict__ partL,
                                                  u16* __restrict__ ob) {
  const int g = blockIdx.x, bh = blockIdx.y;
  const int b = bh >> 4, h = bh & 15;
  const u16* pblk = perm + bh * 1024 + g * 64;
  const int lastv = valid[bh * LL + pblk[63]];
  const int ntiles = ((lastv == 0 ? LL : lastv) + 63) >> 6;
  const int nch = min(3, (ntiles + 5) / 6);  // chunks present (chunk = 6 tiles)
  const int p = threadIdx.x >> 2;          // sorted row 0..63
  const int q4 = (threadIdx.x & 3) * 16;   // col base
  const int s0 = (bh * 16 + g) * 3;

  float m[3], l[3];
  float M = -1e30f;
  for (int c = 0; c < nch; ++c) {
    m[c] = partM[(s0 + c) * 64 + p];
    l[c] = partL[(s0 + c) * 64 + p];
    M = fmaxf(M, m[c]);
  }
  float w[3], L = 0.0f;
  for (int c = 0; c < nch; ++c) {
    w[c] = __builtin_amdgcn_exp2f(m[c] - M);
    L += l[c] * w[c];
  }
  const float inv = 1.0f / L;

  float acc[16];
#pragma unroll
  for (int j = 0; j < 16; ++j) acc[j] = 0.0f;
  for (int c = 0; c < nch; ++c) {
    const u16* po = partO + (long)(s0 + c) * 4096 + p * 64 + q4;
    v8u x0 = *(const v8u*)po;
    v8u x1 = *(const v8u*)(po + 8);
#pragma unroll
    for (int j = 0; j < 8; ++j) acc[j] += b2f(x0[j]) * w[c];
#pragma unroll
    for (int j = 0; j < 8; ++j) acc[8 + j] += b2f(x1[j]) * w[c];
  }
  const int orow = pblk[p];
  u16* dst = ob + ((long)b * LL + orow) * DD + h * 64 + q4;
#pragma unroll
  for (int j = 0; j < 16; ++j) dst[j] = f2b(acc[j] * inv);
}

// ---------------- launch ------------------------------------------------------
extern "C" void kernel_launch(void* const* d_in, const int* in_sizes, int n_in,
                              void* d_out, int out_size, void* d_ws, size_t ws_size,
                              hipStream_t stream) {
  const float* Q = (const float*)d_in[0];
  const float* K = (const float*)d_in[1];
  const float* V = (const float*)d_in[2];
  const int* valid = (const int*)d_in[3];
  const float* Wq = (const float*)d_in[4];
  const float* Wk = (const float*)d_in[5];
  const float* Wv = (const float*)d_in[6];
  const float* Wo = (const float*)d_in[7];
  float* out = (float*)d_out;

  u16* ws = (u16*)d_ws;
  const long MK = 4096L * 1024;
  const long NK = 1024L * 1024;
  u16* qkvb = ws;              // UNUSED pre-attn now (partO home)
  u16* wqkv = qkvb + 3 * MK;   // bf16 Wq,Wk,Wv 3*NK (dead after proj GEMM)
  u16* wo = wqkv + 3 * NK;     // bf16 Wo NK (live until final GEMM)
  u16* proj = wo + NK;         // q,k,v projections 3*MK
  u16* ob = proj + 3 * MK;     // attention output MK
  // dead-region reuse:
  u16* perm = wqkv;                                  // 64*1024 u16 = 128 KB
  u16* partO = qkvb;                                 // 3072 slots*4096 u16 = 25.2 MB
  float* partM = (float*)(wqkv + 64 * 1024);         // 3072*64 f32 = 786 KB
  float* partL = partM + 3072L * 64;                 // 786 KB

  cvt4<<<dim3(512, 4), 256, 0, stream>>>(Wq, Wk, Wv, Wo, wqkv);

  gemm_proj<<<dim3(8, 32, 3), 256, 0, stream>>>(Q, K, V, wqkv, proj);
  sortperm<<<64, 256, 0, stream>>>(valid, perm);
  attn_kern<<<dim3(48, 64), 256, 0, stream>>>(proj, proj + MK, proj + 2 * MK, valid,
                                              perm, partO, partM, partL);
  merge_kern<<<dim3(16, 64), 256, 0, stream>>>(valid, perm, partO, partM, partL, ob);
  gemm_bt64<<<dim3(8, 64), 256, 0, stream>>>(ob, wqkv + 3 * NK, out);
}

// Round 21
// 137.195 us; speedup vs baseline: 1.1281x; 1.1281x over previous
//
#include <hip/hip_runtime.h>
#include <hip/hip_bf16.h>

typedef short v8s __attribute__((ext_vector_type(8)));
typedef unsigned short v8u __attribute__((ext_vector_type(8)));
typedef float v4f __attribute__((ext_vector_type(4)));
typedef unsigned short u16;

#define LL 1024
#define DD 1024

static __device__ __forceinline__ u16 f2b(float x) {
  __hip_bfloat16 h = __float2bfloat16(x);
  return __builtin_bit_cast(u16, h);
}
static __device__ __forceinline__ float b2f(u16 u) {
  unsigned int x = ((unsigned int)u) << 16;
  return __builtin_bit_cast(float, x);
}

static __device__ __forceinline__ void gload_lds16(const u16* g, u16* l) {
  __builtin_amdgcn_global_load_lds((const __attribute__((address_space(1))) void*)g,
                                   (__attribute__((address_space(3))) void*)l, 16, 0, 0);
}

// ---------------- f32 -> bf16 conversion, ALL 7 tensors in one launch --------
__global__ __launch_bounds__(256) void cvt7(const float* __restrict__ p0,
                                            const float* __restrict__ p1,
                                            const float* __restrict__ p2,
                                            const float* __restrict__ p3,
                                            const float* __restrict__ p4,
                                            const float* __restrict__ p5,
                                            const float* __restrict__ p6,
                                            u16* __restrict__ ws) {
  const long MK = 4096L * 1024, NK = 1024L * 1024;
  const int y = blockIdx.y;
  const float* srcs[7] = {p0, p1, p2, p3, p4, p5, p6};
  const float* src = srcs[y];
  u16* dst = (y < 3) ? ws + (long)y * MK : ws + 3 * MK + (long)(y - 3) * NK;
  const int n8 = (y < 3) ? (int)(MK / 8) : (int)(NK / 8);
  int i = blockIdx.x * 256 + threadIdx.x;
  if (i >= n8) return;
  const float4* p = (const float4*)src + (long)i * 2;
  float4 a = p[0], b = p[1];
  v8u r;
  r[0] = f2b(a.x); r[1] = f2b(a.y); r[2] = f2b(a.z); r[3] = f2b(a.w);
  r[4] = f2b(b.x); r[5] = f2b(b.y); r[6] = f2b(b.z); r[7] = f2b(b.w);
  *((v8u*)dst + i) = r;
}

// ---------------- per-head counting sort of q-rows by effective valid len ----
__global__ __launch_bounds__(256) void sortperm(const int* __restrict__ valid,
                                                u16* __restrict__ perm) {
  __shared__ int hist[1024];
  __shared__ int wsum[4];
  const int bh = blockIdx.x;
  const int tid = threadIdx.x;
  const int* v = valid + bh * 1024;
  for (int i = tid; i < 1024; i += 256) hist[i] = 0;
  __syncthreads();
  for (int i = tid; i < 1024; i += 256) {
    int k = v[i];
    k = (k == 0) ? 1023 : (k - 1);  // bin = eff-1
    atomicAdd(&hist[k], 1);
  }
  __syncthreads();
  const int base = tid * 4;
  int h0 = hist[base], h1 = hist[base + 1], h2 = hist[base + 2], h3 = hist[base + 3];
  int local = h0 + h1 + h2 + h3;
  const int lane = tid & 63, w = tid >> 6;
  int scan = local;
#pragma unroll
  for (int d = 1; d < 64; d <<= 1) {
    int t = __shfl_up(scan, d);
    if (lane >= d) scan += t;
  }
  if (lane == 63) wsum[w] = scan;
  __syncthreads();
  int woff = 0;
  for (int i = 0; i < w; ++i) woff += wsum[i];
  int excl = woff + scan - local;
  hist[base] = excl;
  hist[base + 1] = excl + h0;
  hist[base + 2] = excl + h0 + h1;
  hist[base + 3] = excl + h0 + h1 + h2;
  __syncthreads();
  for (int i = tid; i < 1024; i += 256) {
    int k = v[i];
    k = (k == 0) ? 1023 : (k - 1);
    int pos = atomicAdd(&hist[k], 1);
    perm[bh * 1024 + pos] = (u16)i;
  }
}

// ---------------- C[M,N] = A[M,K] * B[N,K]^T, 128x128 tile (proj GEMM) --------
template <typename OUTT>
__global__ __launch_bounds__(256) void gemm_bt(const u16* __restrict__ A,
                                               const u16* __restrict__ Bw,
                                               OUTT* __restrict__ C,
                                               long za, long zb, long zc) {
  __shared__ u16 As[128 * 64];
  __shared__ u16 Bs[128 * 64];
  A += (long)blockIdx.z * za;
  Bw += (long)blockIdx.z * zb;
  C += (long)blockIdx.z * zc;
  const int tid = threadIdx.x;
  const int lane = tid & 63;
  const int l15 = lane & 15, lg = lane >> 4;
  const int wid = tid >> 6;
  const int wm = wid >> 1, wn = wid & 1;
  const long mbase = (long)blockIdx.y * 128;
  const long nbase = (long)blockIdx.x * 128;

  const u16* ap = A + (mbase + (tid >> 3)) * 1024 + (tid & 7) * 8;
  const u16* bp = Bw + (nbase + (tid >> 3)) * 1024 + (tid & 7) * 8;

  v4f acc[4][4] = {};

  for (int kt = 0; kt < 16; ++kt) {
    __syncthreads();
#pragma unroll
    for (int j = 0; j < 4; ++j) {
      gload_lds16(ap + kt * 64 + j * 32 * 1024, &As[(tid + 256 * j) * 8]);
      gload_lds16(bp + kt * 64 + j * 32 * 1024, &Bs[(tid + 256 * j) * 8]);
    }
    __syncthreads();
#pragma unroll
    for (int kk = 0; kk < 2; ++kk) {
      v8s a[4], b[4];
#pragma unroll
      for (int i = 0; i < 4; ++i)
        a[i] = *(const v8s*)&As[(wm * 64 + i * 16 + l15) * 64 + kk * 32 + lg * 8];
#pragma unroll
      for (int i = 0; i < 4; ++i)
        b[i] = *(const v8s*)&Bs[(wn * 64 + i * 16 + l15) * 64 + kk * 32 + lg * 8];
#pragma unroll
      for (int mi = 0; mi < 4; ++mi)
#pragma unroll
        for (int nj = 0; nj < 4; ++nj)
          acc[mi][nj] = __builtin_amdgcn_mfma_f32_16x16x32_bf16(a[mi], b[nj], acc[mi][nj], 0, 0, 0);
    }
  }
#pragma unroll
  for (int mi = 0; mi < 4; ++mi) {
#pragma unroll
    for (int r = 0; r < 4; ++r) {
      long row = mbase + wm * 64 + mi * 16 + lg * 4 + r;
#pragma unroll
      for (int nj = 0; nj < 4; ++nj) {
        long col = nbase + wn * 64 + nj * 16 + l15;
        if constexpr (__is_same(OUTT, float))
          C[row * 1024 + col] = acc[mi][nj][r];
        else
          C[row * 1024 + col] = f2b(acc[mi][nj][r]);
      }
    }
  }
}

// ---------------- C[M,N] = A[M,K] * B[N,K]^T, 64x128 tile (out GEMM) ----------
// 512 blocks = 2/CU -> inter-block overlap hides barrier-drain stalls.
__global__ __launch_bounds__(256) void gemm_bt64(const u16* __restrict__ A,
                                                 const u16* __restrict__ Bw,
                                                 float* __restrict__ C) {
  __shared__ u16 As[64 * 64];
  __shared__ u16 Bs[128 * 64];
  const int tid = threadIdx.x;
  const int lane = tid & 63;
  const int l15 = lane & 15, lg = lane >> 4;
  const int wid = tid >> 6;
  const int wm = wid >> 1, wn = wid & 1;  // wave = 32 rows x 64 cols
  const long mbase = (long)blockIdx.y * 64;
  const long nbase = (long)blockIdx.x * 128;

  const u16* ap = A + (mbase + (tid >> 3)) * 1024 + (tid & 7) * 8;
  const u16* bp = Bw + (nbase + (tid >> 3)) * 1024 + (tid & 7) * 8;

  v4f acc[2][4] = {};

  for (int kt = 0; kt < 16; ++kt) {
    __syncthreads();
#pragma unroll
    for (int j = 0; j < 2; ++j)
      gload_lds16(ap + kt * 64 + j * 32 * 1024, &As[(tid + 256 * j) * 8]);
#pragma unroll
    for (int j = 0; j < 4; ++j)
      gload_lds16(bp + kt * 64 + j * 32 * 1024, &Bs[(tid + 256 * j) * 8]);
    __syncthreads();
#pragma unroll
    for (int kk = 0; kk < 2; ++kk) {
      v8s a[2], b[4];
#pragma unroll
      for (int i = 0; i < 2; ++i)
        a[i] = *(const v8s*)&As[(wm * 32 + i * 16 + l15) * 64 + kk * 32 + lg * 8];
#pragma unroll
      for (int i = 0; i < 4; ++i)
        b[i] = *(const v8s*)&Bs[(wn * 64 + i * 16 + l15) * 64 + kk * 32 + lg * 8];
#pragma unroll
      for (int mi = 0; mi < 2; ++mi)
#pragma unroll
        for (int nj = 0; nj < 4; ++nj)
          acc[mi][nj] = __builtin_amdgcn_mfma_f32_16x16x32_bf16(a[mi], b[nj], acc[mi][nj], 0, 0, 0);
    }
  }
#pragma unroll
  for (int mi = 0; mi < 2; ++mi) {
#pragma unroll
    for (int r = 0; r < 4; ++r) {
      long row = mbase + wm * 32 + mi * 16 + lg * 4 + r;
#pragma unroll
      for (int nj = 0; nj < 4; ++nj) {
        long col = nbase + wn * 64 + nj * 16 + l15;
        C[row * 1024 + col] = acc[mi][nj][r];
      }
    }
  }
}

// ---------------- fused masked attention, split-K x3 (chunk=6 tiles) ----------
__global__ __launch_bounds__(256) void attn_kern(const u16* __restrict__ qb,
                                                 const u16* __restrict__ kb,
                                                 const u16* __restrict__ vb,
                                                 const int* __restrict__ valid,
                                                 const u16* __restrict__ perm,
                                                 u16* __restrict__ partO,
                                                 float* __restrict__ partM,
                                                 float* __restrict__ partL) {
  __shared__ u16 Ks[64 * 72];       // [key][hd], +8 pad -> no 16-way conflict
  __shared__ u16 Vt[64 * 72];       // [hd][key], transposed for PV B-operand
  __shared__ u16 Ps[4][16 * 72];    // per-wave P tile [q][key]

  const int tid = threadIdx.x;
  const int lane = tid & 63;
  const int wid = tid >> 6;
  const int l15 = lane & 15, lg = lane >> 4;
  const int bh = blockIdx.y;
  const int b = bh >> 4, h = bh & 15;
  const long headoff = ((long)b * LL) * DD + h * 64;
  const int xx = blockIdx.x;
  const int gq = 15 - (xx / 3);    // heaviest sorted group dispatched first
  const int ch = xx % 3;
  const u16* pblk = perm + bh * 1024 + gq * 64;

  const int lastv = valid[bh * LL + pblk[63]];
  const int ntiles = ((lastv == 0 ? LL : lastv) + 63) >> 6;
  const int kt0 = ch * 6;
  const int kt1 = min(ntiles, kt0 + 6);
  if (kt0 >= kt1) return;  // chunk absent for lighter groups
  const int slot = (bh * 16 + gq) * 3 + ch;

  const u16* pp = pblk + wid * 16;

  // Q A-fragments (rows via perm) live in registers for the whole kernel
  const int qrowA = pp[l15];
  v8s qf[2];
#pragma unroll
  for (int ks = 0; ks < 2; ++ks)
    qf[ks] = *(const v8s*)(qb + headoff + (long)qrowA * DD + ks * 32 + lg * 8);

  // per-lane C-frag rows (lg*4+r): raw valid for masking
  int vraw[4];
#pragma unroll
  for (int r = 0; r < 4; ++r) vraw[r] = valid[bh * LL + pp[lg * 4 + r]];

  float mrow[4], lrow[4];
  v4f oacc[4] = {};
#pragma unroll
  for (int r = 0; r < 4; ++r) { mrow[r] = -1e30f; lrow[r] = 0.0f; }

  const int kk = tid & 63;   // staging: key row
  const int qtr = tid >> 6;  // staging: 16-wide hd quarter
  const long stagebase = headoff + (long)kk * DD + qtr * 16;

  // prologue: issue first tile's K/V loads (reg staging, write-late)
  v8s rk0 = *(const v8s*)(kb + stagebase + (long)kt0 * 64 * DD);
  v8s rk1 = *(const v8s*)(kb + stagebase + (long)kt0 * 64 * DD + 8);
  v8s rv0 = *(const v8s*)(vb + stagebase + (long)kt0 * 64 * DD);
  v8s rv1 = *(const v8s*)(vb + stagebase + (long)kt0 * 64 * DD + 8);

  for (int kt = kt0; kt < kt1; ++kt) {
    // ---- barrier A (WAR guard): raw s_barrier, no vmcnt drain.
    __builtin_amdgcn_sched_barrier(0);
    __builtin_amdgcn_s_barrier();
    __builtin_amdgcn_sched_barrier(0);

    // commit staged regs -> LDS (compiler inserts COUNTED vmcnt for rk*/rv*)
    *(v8s*)&Ks[kk * 72 + qtr * 16] = rk0;
    *(v8s*)&Ks[kk * 72 + qtr * 16 + 8] = rk1;
    {
      v8u u0 = __builtin_bit_cast(v8u, rv0);
      v8u u1 = __builtin_bit_cast(v8u, rv1);
#pragma unroll
      for (int j = 0; j < 8; ++j) Vt[(qtr * 16 + j) * 72 + kk] = u0[j];
#pragma unroll
      for (int j = 0; j < 8; ++j) Vt[(qtr * 16 + 8 + j) * 72 + kk] = u1[j];
    }
    // prefetch next tile's K/V; stays in flight across barrier B + compute
    if (kt + 1 < kt1) {
      const long noff = stagebase + (long)(kt + 1) * 64 * DD;
      rk0 = *(const v8s*)(kb + noff);
      rk1 = *(const v8s*)(kb + noff + 8);
      rv0 = *(const v8s*)(vb + noff);
      rv1 = *(const v8s*)(vb + noff + 8);
    }
    // ---- barrier B: ds_writes visible; vmcnt NOT drained.
    asm volatile("s_waitcnt lgkmcnt(0)" ::: "memory");
    __builtin_amdgcn_sched_barrier(0);
    __builtin_amdgcn_s_barrier();
    __builtin_amdgcn_sched_barrier(0);

    // S = Q K^T for 16 q rows x 64 keys
    v4f s[4];
    __builtin_amdgcn_s_setprio(1);
#pragma unroll
    for (int t = 0; t < 4; ++t) {
      v4f z = {};
#pragma unroll
      for (int ks = 0; ks < 2; ++ks) {
        v8s kf = *(const v8s*)&Ks[(t * 16 + l15) * 72 + ks * 32 + lg * 8];
        z = __builtin_amdgcn_mfma_f32_16x16x32_bf16(qf[ks], kf, z, 0, 0, 0);
      }
      s[t] = z;
    }
    __builtin_amdgcn_s_setprio(0);

    // scale into log2 domain + mask (ref semantics: -1e6, col < valid_raw)
    const float SC = 0.18033688f;  // (1/8) * log2(e)
    const int colbase = kt * 64 + l15;
#pragma unroll
    for (int t = 0; t < 4; ++t)
#pragma unroll
      for (int r = 0; r < 4; ++r) {
        float val = s[t][r] * SC;
        s[t][r] = (colbase + t * 16 < vraw[r]) ? val : -1e6f;
      }

    // online softmax (log2 domain) with defer-max: rescale only if max grew >11
    float pm[4];
#pragma unroll
    for (int r = 0; r < 4; ++r)
      pm[r] = fmaxf(fmaxf(s[0][r], s[1][r]), fmaxf(s[2][r], s[3][r]));
#pragma unroll
    for (int d = 1; d < 16; d <<= 1)
#pragma unroll
      for (int r = 0; r < 4; ++r) pm[r] = fmaxf(pm[r], __shfl_xor(pm[r], d));

    bool sk = true;
#pragma unroll
    for (int r = 0; r < 4; ++r) sk = sk && (pm[r] <= mrow[r] + 11.0f);
    if (!__all(sk)) {
#pragma unroll
      for (int r = 0; r < 4; ++r) {
        float mn = fmaxf(mrow[r], pm[r]);
        float sc = __builtin_amdgcn_exp2f(mrow[r] - mn);
        mrow[r] = mn;
        lrow[r] *= sc;
#pragma unroll
        for (int t = 0; t < 4; ++t) oacc[t][r] *= sc;
      }
    }
    float rs[4] = {0.f, 0.f, 0.f, 0.f};
#pragma unroll
    for (int t = 0; t < 4; ++t)
#pragma unroll
      for (int r = 0; r < 4; ++r) {
        float p = __builtin_amdgcn_exp2f(s[t][r] - mrow[r]);
        s[t][r] = p;
        rs[r] += p;
      }
#pragma unroll
    for (int d = 1; d < 16; d <<= 1)
#pragma unroll
      for (int r = 0; r < 4; ++r) rs[r] += __shfl_xor(rs[r], d);
#pragma unroll
    for (int r = 0; r < 4; ++r) lrow[r] += rs[r];

    // P -> bf16 -> per-wave LDS, then consume as MFMA A-operand
#pragma unroll
    for (int t = 0; t < 4; ++t)
#pragma unroll
      for (int r = 0; r < 4; ++r)
        Ps[wid][(lg * 4 + r) * 72 + t * 16 + l15] = f2b(s[t][r]);

    asm volatile("s_waitcnt lgkmcnt(0)" ::: "memory");
    __builtin_amdgcn_sched_barrier(0);

    __builtin_amdgcn_s_setprio(1);
#pragma unroll
    for (int ks = 0; ks < 2; ++ks) {
      v8s pa = *(const v8s*)&Ps[wid][l15 * 72 + ks * 32 + lg * 8];
#pragma unroll
      for (int t = 0; t < 4; ++t) {
        v8s vf = *(const v8s*)&Vt[(t * 16 + l15) * 72 + ks * 32 + lg * 8];
        oacc[t] = __builtin_amdgcn_mfma_f32_16x16x32_bf16(pa, vf, oacc[t], 0, 0, 0);
      }
    }
    __builtin_amdgcn_s_setprio(0);
  }

  // epilogue: write UNNORMALIZED partials (sorted-row order); merge normalizes
  u16* po = partO + (long)slot * 4096;
  float* pmv = partM + slot * 64;
  float* plv = partL + slot * 64;
#pragma unroll
  for (int r = 0; r < 4; ++r) {
    int p = wid * 16 + lg * 4 + r;
    pmv[p] = mrow[r];
    plv[p] = lrow[r];
#pragma unroll
    for (int t = 0; t < 4; ++t)
      po[p * 64 + t * 16 + l15] = f2b(oacc[t][r]);
  }
}

// ---------------- merge the (up to 3) chunk partials per (bh, group) ----------
__global__ __launch_bounds__(256) void merge_kern(const int* __restrict__ valid,
                                                  const u16* __restrict__ perm,
                                                  const u16* __restrict__ partO,
                                                  const float* __restrict__ partM,
                                                  const float* __restrict__ partL,
                                                  u16* __restrict__ ob) {
  const int g = blockIdx.x, bh = blockIdx.y;
  const int b = bh >> 4, h = bh & 15;
  const u16* pblk = perm + bh * 1024 + g * 64;
  const int lastv = valid[bh * LL + pblk[63]];
  const int ntiles = ((lastv == 0 ? LL : lastv) + 63) >> 6;
  const int nch = min(3, (ntiles + 5) / 6);  // chunks present (chunk = 6 tiles)
  const int p = threadIdx.x >> 2;          // sorted row 0..63
  const int q4 = (threadIdx.x & 3) * 16;   // col base
  const int s0 = (bh * 16 + g) * 3;

  float m[3], l[3];
  float M = -1e30f;
  for (int c = 0; c < nch; ++c) {
    m[c] = partM[(s0 + c) * 64 + p];
    l[c] = partL[(s0 + c) * 64 + p];
    M = fmaxf(M, m[c]);
  }
  float w[3], L = 0.0f;
  for (int c = 0; c < nch; ++c) {
    w[c] = __builtin_amdgcn_exp2f(m[c] - M);
    L += l[c] * w[c];
  }
  const float inv = 1.0f / L;

  float acc[16];
#pragma unroll
  for (int j = 0; j < 16; ++j) acc[j] = 0.0f;
  for (int c = 0; c < nch; ++c) {
    const u16* po = partO + (long)(s0 + c) * 4096 + p * 64 + q4;
    v8u x0 = *(const v8u*)po;
    v8u x1 = *(const v8u*)(po + 8);
#pragma unroll
    for (int j = 0; j < 8; ++j) acc[j] += b2f(x0[j]) * w[c];
#pragma unroll
    for (int j = 0; j < 8; ++j) acc[8 + j] += b2f(x1[j]) * w[c];
  }
  const int orow = pblk[p];
  u16* dst = ob + ((long)b * LL + orow) * DD + h * 64 + q4;
#pragma unroll
  for (int j = 0; j < 16; ++j) dst[j] = f2b(acc[j] * inv);
}

// ---------------- launch ------------------------------------------------------
extern "C" void kernel_launch(void* const* d_in, const int* in_sizes, int n_in,
                              void* d_out, int out_size, void* d_ws, size_t ws_size,
                              hipStream_t stream) {
  const float* Q = (const float*)d_in[0];
  const float* K = (const float*)d_in[1];
  const float* V = (const float*)d_in[2];
  const int* valid = (const int*)d_in[3];
  const float* Wq = (const float*)d_in[4];
  const float* Wk = (const float*)d_in[5];
  const float* Wv = (const float*)d_in[6];
  const float* Wo = (const float*)d_in[7];
  float* out = (float*)d_out;

  u16* ws = (u16*)d_ws;
  const long MK = 4096L * 1024;
  const long NK = 1024L * 1024;
  u16* qkvb = ws;              // bf16 Q,K,V  3*MK (dead after proj GEMM)
  u16* wqkv = qkvb + 3 * MK;   // bf16 Wq,Wk,Wv 3*NK (dead after proj GEMM)
  u16* wo = wqkv + 3 * NK;     // bf16 Wo NK
  u16* proj = wo + NK;         // q,k,v projections 3*MK
  u16* ob = proj + 3 * MK;     // attention output MK
  // dead-region reuse after proj GEMM:
  u16* perm = wqkv;                                  // 64*1024 u16 = 128 KB
  u16* partO = qkvb;                                 // 3072 slots*4096 u16 = 25.2 MB (exact fit)
  float* partM = (float*)(wqkv + 64 * 1024);         // 3072*64 f32 = 786 KB
  float* partL = partM + 3072L * 64;                 // 786 KB

  cvt7<<<dim3(2048, 7), 256, 0, stream>>>(Q, K, V, Wq, Wk, Wv, Wo, ws);

  gemm_bt<u16><<<dim3(8, 32, 3), 256, 0, stream>>>(qkvb, wqkv, proj, MK, NK, MK);
  sortperm<<<64, 256, 0, stream>>>(valid, perm);
  attn_kern<<<dim3(48, 64), 256, 0, stream>>>(proj, proj + MK, proj + 2 * MK, valid,
                                              perm, partO, partM, partL);
  merge_kern<<<dim3(16, 64), 256, 0, stream>>>(valid, perm, partO, partM, partL, ob);
  gemm_bt64<<<dim3(8, 64), 256, 0, stream>>>(ob, wo, out);
}

// Round 23
// 135.671 us; speedup vs baseline: 1.1408x; 1.0112x over previous
//
#include <hip/hip_runtime.h>
#include <hip/hip_bf16.h>

typedef short v8s __attribute__((ext_vector_type(8)));
typedef unsigned short v8u __attribute__((ext_vector_type(8)));
typedef float v4f __attribute__((ext_vector_type(4)));
typedef unsigned short u16;

#define LL 1024
#define DD 1024

static __device__ __forceinline__ u16 f2b(float x) {
  __hip_bfloat16 h = __float2bfloat16(x);
  return __builtin_bit_cast(u16, h);
}
static __device__ __forceinline__ float b2f(u16 u) {
  unsigned int x = ((unsigned int)u) << 16;
  return __builtin_bit_cast(float, x);
}

static __device__ __forceinline__ void gload_lds16(const u16* g, u16* l) {
  __builtin_amdgcn_global_load_lds((const __attribute__((address_space(1))) void*)g,
                                   (__attribute__((address_space(3))) void*)l, 16, 0, 0);
}

// ---------------- f32 -> bf16 conversion, ALL 7 tensors in one launch --------
__global__ __launch_bounds__(256) void cvt7(const float* __restrict__ p0,
                                            const float* __restrict__ p1,
                                            const float* __restrict__ p2,
                                            const float* __restrict__ p3,
                                            const float* __restrict__ p4,
                                            const float* __restrict__ p5,
                                            const float* __restrict__ p6,
                                            u16* __restrict__ ws) {
  const long MK = 4096L * 1024, NK = 1024L * 1024;
  const int y = blockIdx.y;
  const float* srcs[7] = {p0, p1, p2, p3, p4, p5, p6};
  const float* src = srcs[y];
  u16* dst = (y < 3) ? ws + (long)y * MK : ws + 3 * MK + (long)(y - 3) * NK;
  const int n8 = (y < 3) ? (int)(MK / 8) : (int)(NK / 8);
  int i = blockIdx.x * 256 + threadIdx.x;
  if (i >= n8) return;
  const float4* p = (const float4*)src + (long)i * 2;
  float4 a = p[0], b = p[1];
  v8u r;
  r[0] = f2b(a.x); r[1] = f2b(a.y); r[2] = f2b(a.z); r[3] = f2b(a.w);
  r[4] = f2b(b.x); r[5] = f2b(b.y); r[6] = f2b(b.z); r[7] = f2b(b.w);
  *((v8u*)dst + i) = r;
}

// ---------------- per-head counting sort of q-rows by effective valid len ----
__global__ __launch_bounds__(256) void sortperm(const int* __restrict__ valid,
                                                u16* __restrict__ perm) {
  __shared__ int hist[1024];
  __shared__ int wsum[4];
  const int bh = blockIdx.x;
  const int tid = threadIdx.x;
  const int* v = valid + bh * 1024;
  for (int i = tid; i < 1024; i += 256) hist[i] = 0;
  __syncthreads();
  for (int i = tid; i < 1024; i += 256) {
    int k = v[i];
    k = (k == 0) ? 1023 : (k - 1);  // bin = eff-1
    atomicAdd(&hist[k], 1);
  }
  __syncthreads();
  const int base = tid * 4;
  int h0 = hist[base], h1 = hist[base + 1], h2 = hist[base + 2], h3 = hist[base + 3];
  int local = h0 + h1 + h2 + h3;
  const int lane = tid & 63, w = tid >> 6;
  int scan = local;
#pragma unroll
  for (int d = 1; d < 64; d <<= 1) {
    int t = __shfl_up(scan, d);
    if (lane >= d) scan += t;
  }
  if (lane == 63) wsum[w] = scan;
  __syncthreads();
  int woff = 0;
  for (int i = 0; i < w; ++i) woff += wsum[i];
  int excl = woff + scan - local;
  hist[base] = excl;
  hist[base + 1] = excl + h0;
  hist[base + 2] = excl + h0 + h1;
  hist[base + 3] = excl + h0 + h1 + h2;
  __syncthreads();
  for (int i = tid; i < 1024; i += 256) {
    int k = v[i];
    k = (k == 0) ? 1023 : (k - 1);
    int pos = atomicAdd(&hist[k], 1);
    perm[bh * 1024 + pos] = (u16)i;
  }
}

// ---------------- C[M,N] = A[M,K] * B[N,K]^T, 128x128 tile (proj GEMM) --------
template <typename OUTT>
__global__ __launch_bounds__(256) void gemm_bt(const u16* __restrict__ A,
                                               const u16* __restrict__ Bw,
                                               OUTT* __restrict__ C,
                                               long za, long zb, long zc) {
  __shared__ u16 As[128 * 64];
  __shared__ u16 Bs[128 * 64];
  A += (long)blockIdx.z * za;
  Bw += (long)blockIdx.z * zb;
  C += (long)blockIdx.z * zc;
  const int tid = threadIdx.x;
  const int lane = tid & 63;
  const int l15 = lane & 15, lg = lane >> 4;
  const int wid = tid >> 6;
  const int wm = wid >> 1, wn = wid & 1;
  const long mbase = (long)blockIdx.y * 128;
  const long nbase = (long)blockIdx.x * 128;

  const u16* ap = A + (mbase + (tid >> 3)) * 1024 + (tid & 7) * 8;
  const u16* bp = Bw + (nbase + (tid >> 3)) * 1024 + (tid & 7) * 8;

  v4f acc[4][4] = {};

  for (int kt = 0; kt < 16; ++kt) {
    __syncthreads();
#pragma unroll
    for (int j = 0; j < 4; ++j) {
      gload_lds16(ap + kt * 64 + j * 32 * 1024, &As[(tid + 256 * j) * 8]);
      gload_lds16(bp + kt * 64 + j * 32 * 1024, &Bs[(tid + 256 * j) * 8]);
    }
    __syncthreads();
#pragma unroll
    for (int kk = 0; kk < 2; ++kk) {
      v8s a[4], b[4];
#pragma unroll
      for (int i = 0; i < 4; ++i)
        a[i] = *(const v8s*)&As[(wm * 64 + i * 16 + l15) * 64 + kk * 32 + lg * 8];
#pragma unroll
      for (int i = 0; i < 4; ++i)
        b[i] = *(const v8s*)&Bs[(wn * 64 + i * 16 + l15) * 64 + kk * 32 + lg * 8];
#pragma unroll
      for (int mi = 0; mi < 4; ++mi)
#pragma unroll
        for (int nj = 0; nj < 4; ++nj)
          acc[mi][nj] = __builtin_amdgcn_mfma_f32_16x16x32_bf16(a[mi], b[nj], acc[mi][nj], 0, 0, 0);
    }
  }
#pragma unroll
  for (int mi = 0; mi < 4; ++mi) {
#pragma unroll
    for (int r = 0; r < 4; ++r) {
      long row = mbase + wm * 64 + mi * 16 + lg * 4 + r;
#pragma unroll
      for (int nj = 0; nj < 4; ++nj) {
        long col = nbase + wn * 64 + nj * 16 + l15;
        if constexpr (__is_same(OUTT, float))
          C[row * 1024 + col] = acc[mi][nj][r];
        else
          C[row * 1024 + col] = f2b(acc[mi][nj][r]);
      }
    }
  }
}

// ---------------- C[M,N] = A[M,K] * B[N,K]^T, 64x64 tile (out GEMM) -----------
// grid (16, 64): 1024 blocks = 4/CU (16 KB LDS) -> deeper latency-packing than
// the 2/CU 64x128 version (round-17 lesson: latency regime favors resident
// blocks). Same K-loop accumulation order -> bitwise-identical output.
__global__ __launch_bounds__(256) void gemm_bt64(const u16* __restrict__ A,
                                                 const u16* __restrict__ Bw,
                                                 float* __restrict__ C) {
  __shared__ u16 As[64 * 64];
  __shared__ u16 Bs[64 * 64];
  const int tid = threadIdx.x;
  const int lane = tid & 63;
  const int l15 = lane & 15, lg = lane >> 4;
  const int wid = tid >> 6;
  const int wm = wid >> 1, wn = wid & 1;  // wave = 32 rows x 32 cols
  const long mbase = (long)blockIdx.y * 64;
  const long nbase = (long)blockIdx.x * 64;

  const u16* ap = A + (mbase + (tid >> 3)) * 1024 + (tid & 7) * 8;
  const u16* bp = Bw + (nbase + (tid >> 3)) * 1024 + (tid & 7) * 8;

  v4f acc[2][2] = {};

  for (int kt = 0; kt < 16; ++kt) {
    __syncthreads();
#pragma unroll
    for (int j = 0; j < 2; ++j) {
      gload_lds16(ap + kt * 64 + j * 32 * 1024, &As[(tid + 256 * j) * 8]);
      gload_lds16(bp + kt * 64 + j * 32 * 1024, &Bs[(tid + 256 * j) * 8]);
    }
    __syncthreads();
#pragma unroll
    for (int kk = 0; kk < 2; ++kk) {
      v8s a[2], b[2];
#pragma unroll
      for (int i = 0; i < 2; ++i)
        a[i] = *(const v8s*)&As[(wm * 32 + i * 16 + l15) * 64 + kk * 32 + lg * 8];
#pragma unroll
      for (int i = 0; i < 2; ++i)
        b[i] = *(const v8s*)&Bs[(wn * 32 + i * 16 + l15) * 64 + kk * 32 + lg * 8];
#pragma unroll
      for (int mi = 0; mi < 2; ++mi)
#pragma unroll
        for (int nj = 0; nj < 2; ++nj)
          acc[mi][nj] = __builtin_amdgcn_mfma_f32_16x16x32_bf16(a[mi], b[nj], acc[mi][nj], 0, 0, 0);
    }
  }
#pragma unroll
  for (int mi = 0; mi < 2; ++mi) {
#pragma unroll
    for (int r = 0; r < 4; ++r) {
      long row = mbase + wm * 32 + mi * 16 + lg * 4 + r;
#pragma unroll
      for (int nj = 0; nj < 2; ++nj) {
        long col = nbase + wn * 32 + nj * 16 + l15;
        C[row * 1024 + col] = acc[mi][nj][r];
      }
    }
  }
}

// ---------------- fused masked attention, split-K x3 (chunk=6 tiles) ----------
__global__ __launch_bounds__(256) void attn_kern(const u16* __restrict__ qb,
                                                 const u16* __restrict__ kb,
                                                 const u16* __restrict__ vb,
                                                 const int* __restrict__ valid,
                                                 const u16* __restrict__ perm,
                                                 u16* __restrict__ partO,
                                                 float* __restrict__ partM,
                                                 float* __restrict__ partL) {
  __shared__ u16 Ks[64 * 72];       // [key][hd], +8 pad -> no 16-way conflict
  __shared__ u16 Vt[64 * 72];       // [hd][key], transposed for PV B-operand
  __shared__ u16 Ps[4][16 * 72];    // per-wave P tile [q][key]

  const int tid = threadIdx.x;
  const int lane = tid & 63;
  const int wid = tid >> 6;
  const int l15 = lane & 15, lg = lane >> 4;
  const int bh = blockIdx.y;
  const int b = bh >> 4, h = bh & 15;
  const long headoff = ((long)b * LL) * DD + h * 64;
  const int xx = blockIdx.x;
  const int gq = 15 - (xx / 3);    // heaviest sorted group dispatched first
  const int ch = xx % 3;
  const u16* pblk = perm + bh * 1024 + gq * 64;

  const int lastv = valid[bh * LL + pblk[63]];
  const int ntiles = ((lastv == 0 ? LL : lastv) + 63) >> 6;
  const int kt0 = ch * 6;
  const int kt1 = min(ntiles, kt0 + 6);
  if (kt0 >= kt1) return;  // chunk absent for lighter groups
  const int slot = (bh * 16 + gq) * 3 + ch;

  const u16* pp = pblk + wid * 16;

  // Q A-fragments (rows via perm) live in registers for the whole kernel
  const int qrowA = pp[l15];
  v8s qf[2];
#pragma unroll
  for (int ks = 0; ks < 2; ++ks)
    qf[ks] = *(const v8s*)(qb + headoff + (long)qrowA * DD + ks * 32 + lg * 8);

  // per-lane C-frag rows (lg*4+r): raw valid for masking
  int vraw[4];
#pragma unroll
  for (int r = 0; r < 4; ++r) vraw[r] = valid[bh * LL + pp[lg * 4 + r]];

  float mrow[4], lrow[4];
  v4f oacc[4] = {};
#pragma unroll
  for (int r = 0; r < 4; ++r) { mrow[r] = -1e30f; lrow[r] = 0.0f; }

  const int kk = tid & 63;   // staging: key row
  const int qtr = tid >> 6;  // staging: 16-wide hd quarter
  const long stagebase = headoff + (long)kk * DD + qtr * 16;

  // prologue: issue first tile's K/V loads (reg staging, write-late)
  v8s rk0 = *(const v8s*)(kb + stagebase + (long)kt0 * 64 * DD);
  v8s rk1 = *(const v8s*)(kb + stagebase + (long)kt0 * 64 * DD + 8);
  v8s rv0 = *(const v8s*)(vb + stagebase + (long)kt0 * 64 * DD);
  v8s rv1 = *(const v8s*)(vb + stagebase + (long)kt0 * 64 * DD + 8);

  for (int kt = kt0; kt < kt1; ++kt) {
    // ---- barrier A (WAR guard): raw s_barrier, no vmcnt drain.
    __builtin_amdgcn_sched_barrier(0);
    __builtin_amdgcn_s_barrier();
    __builtin_amdgcn_sched_barrier(0);

    // commit staged regs -> LDS (compiler inserts COUNTED vmcnt for rk*/rv*)
    *(v8s*)&Ks[kk * 72 + qtr * 16] = rk0;
    *(v8s*)&Ks[kk * 72 + qtr * 16 + 8] = rk1;
    {
      v8u u0 = __builtin_bit_cast(v8u, rv0);
      v8u u1 = __builtin_bit_cast(v8u, rv1);
#pragma unroll
      for (int j = 0; j < 8; ++j) Vt[(qtr * 16 + j) * 72 + kk] = u0[j];
#pragma unroll
      for (int j = 0; j < 8; ++j) Vt[(qtr * 16 + 8 + j) * 72 + kk] = u1[j];
    }
    // prefetch next tile's K/V; stays in flight across barrier B + compute
    if (kt + 1 < kt1) {
      const long noff = stagebase + (long)(kt + 1) * 64 * DD;
      rk0 = *(const v8s*)(kb + noff);
      rk1 = *(const v8s*)(kb + noff + 8);
      rv0 = *(const v8s*)(vb + noff);
      rv1 = *(const v8s*)(vb + noff + 8);
    }
    // ---- barrier B: ds_writes visible; vmcnt NOT drained.
    asm volatile("s_waitcnt lgkmcnt(0)" ::: "memory");
    __builtin_amdgcn_sched_barrier(0);
    __builtin_amdgcn_s_barrier();
    __builtin_amdgcn_sched_barrier(0);

    // S = Q K^T for 16 q rows x 64 keys
    v4f s[4];
    __builtin_amdgcn_s_setprio(1);
#pragma unroll
    for (int t = 0; t < 4; ++t) {
      v4f z = {};
#pragma unroll
      for (int ks = 0; ks < 2; ++ks) {
        v8s kf = *(const v8s*)&Ks[(t * 16 + l15) * 72 + ks * 32 + lg * 8];
        z = __builtin_amdgcn_mfma_f32_16x16x32_bf16(qf[ks], kf, z, 0, 0, 0);
      }
      s[t] = z;
    }
    __builtin_amdgcn_s_setprio(0);

    // scale into log2 domain + mask (ref semantics: -1e6, col < valid_raw)
    const float SC = 0.18033688f;  // (1/8) * log2(e)
    const int colbase = kt * 64 + l15;
#pragma unroll
    for (int t = 0; t < 4; ++t)
#pragma unroll
      for (int r = 0; r < 4; ++r) {
        float val = s[t][r] * SC;
        s[t][r] = (colbase + t * 16 < vraw[r]) ? val : -1e6f;
      }

    // online softmax (log2 domain) with defer-max: rescale only if max grew >11
    float pm[4];
#pragma unroll
    for (int r = 0; r < 4; ++r)
      pm[r] = fmaxf(fmaxf(s[0][r], s[1][r]), fmaxf(s[2][r], s[3][r]));
#pragma unroll
    for (int d = 1; d < 16; d <<= 1)
#pragma unroll
      for (int r = 0; r < 4; ++r) pm[r] = fmaxf(pm[r], __shfl_xor(pm[r], d));

    bool sk = true;
#pragma unroll
    for (int r = 0; r < 4; ++r) sk = sk && (pm[r] <= mrow[r] + 11.0f);
    if (!__all(sk)) {
#pragma unroll
      for (int r = 0; r < 4; ++r) {
        float mn = fmaxf(mrow[r], pm[r]);
        float sc = __builtin_amdgcn_exp2f(mrow[r] - mn);
        mrow[r] = mn;
        lrow[r] *= sc;
#pragma unroll
        for (int t = 0; t < 4; ++t) oacc[t][r] *= sc;
      }
    }
    float rs[4] = {0.f, 0.f, 0.f, 0.f};
#pragma unroll
    for (int t = 0; t < 4; ++t)
#pragma unroll
      for (int r = 0; r < 4; ++r) {
        float p = __builtin_amdgcn_exp2f(s[t][r] - mrow[r]);
        s[t][r] = p;
        rs[r] += p;
      }
#pragma unroll
    for (int d = 1; d < 16; d <<= 1)
#pragma unroll
      for (int r = 0; r < 4; ++r) rs[r] += __shfl_xor(rs[r], d);
#pragma unroll
    for (int r = 0; r < 4; ++r) lrow[r] += rs[r];

    // P -> bf16 -> per-wave LDS, then consume as MFMA A-operand
#pragma unroll
    for (int t = 0; t < 4; ++t)
#pragma unroll
      for (int r = 0; r < 4; ++r)
        Ps[wid][(lg * 4 + r) * 72 + t * 16 + l15] = f2b(s[t][r]);

    asm volatile("s_waitcnt lgkmcnt(0)" ::: "memory");
    __builtin_amdgcn_sched_barrier(0);

    __builtin_amdgcn_s_setprio(1);
#pragma unroll
    for (int ks = 0; ks < 2; ++ks) {
      v8s pa = *(const v8s*)&Ps[wid][l15 * 72 + ks * 32 + lg * 8];
#pragma unroll
      for (int t = 0; t < 4; ++t) {
        v8s vf = *(const v8s*)&Vt[(t * 16 + l15) * 72 + ks * 32 + lg * 8];
        oacc[t] = __builtin_amdgcn_mfma_f32_16x16x32_bf16(pa, vf, oacc[t], 0, 0, 0);
      }
    }
    __builtin_amdgcn_s_setprio(0);
  }

  // epilogue: write UNNORMALIZED partials (sorted-row order); merge normalizes
  u16* po = partO + (long)slot * 4096;
  float* pmv = partM + slot * 64;
  float* plv = partL + slot * 64;
#pragma unroll
  for (int r = 0; r < 4; ++r) {
    int p = wid * 16 + lg * 4 + r;
    pmv[p] = mrow[r];
    plv[p] = lrow[r];
#pragma unroll
    for (int t = 0; t < 4; ++t)
      po[p * 64 + t * 16 + l15] = f2b(oacc[t][r]);
  }
}

// ---------------- merge the (up to 3) chunk partials per (bh, group) ----------
__global__ __launch_bounds__(256) void merge_kern(const int* __restrict__ valid,
                                                  const u16* __restrict__ perm,
                                                  const u16* __restrict__ partO,
                                                  const float* __restrict__ partM,
                                                  const float* __restrict__ partL,
                                                  u16* __restrict__ ob) {
  const int g = blockIdx.x, bh = blockIdx.y;
  const int b = bh >> 4, h = bh & 15;
  const u16* pblk = perm + bh * 1024 + g * 64;
  const int lastv = valid[bh * LL + pblk[63]];
  const int ntiles = ((lastv == 0 ? LL : lastv) + 63) >> 6;
  const int nch = min(3, (ntiles + 5) / 6);  // chunks present (chunk = 6 tiles)
  const int p = threadIdx.x >> 2;          // sorted row 0..63
  const int q4 = (threadIdx.x & 3) * 16;   // col base
  const int s0 = (bh * 16 + g) * 3;

  float m[3], l[3];
  float M = -1e30f;
  for (int c = 0; c < nch; ++c) {
    m[c] = partM[(s0 + c) * 64 + p];
    l[c] = partL[(s0 + c) * 64 + p];
    M = fmaxf(M, m[c]);
  }
  float w[3], L = 0.0f;
  for (int c = 0; c < nch; ++c) {
    w[c] = __builtin_amdgcn_exp2f(m[c] - M);
    L += l[c] * w[c];
  }
  const float inv = 1.0f / L;

  float acc[16];
#pragma unroll
  for (int j = 0; j < 16; ++j) acc[j] = 0.0f;
  for (int c = 0; c < nch; ++c) {
    const u16* po = partO + (long)(s0 + c) * 4096 + p * 64 + q4;
    v8u x0 = *(const v8u*)po;
    v8u x1 = *(const v8u*)(po + 8);
#pragma unroll
    for (int j = 0; j < 8; ++j) acc[j] += b2f(x0[j]) * w[c];
#pragma unroll
    for (int j = 0; j < 8; ++j) acc[8 + j] += b2f(x1[j]) * w[c];
  }
  const int orow = pblk[p];
  u16* dst = ob + ((long)b * LL + orow) * DD + h * 64 + q4;
#pragma unroll
  for (int j = 0; j < 16; ++j) dst[j] = f2b(acc[j] * inv);
}

// ---------------- launch ------------------------------------------------------
extern "C" void kernel_launch(void* const* d_in, const int* in_sizes, int n_in,
                              void* d_out, int out_size, void* d_ws, size_t ws_size,
                              hipStream_t stream) {
  const float* Q = (const float*)d_in[0];
  const float* K = (const float*)d_in[1];
  const float* V = (const float*)d_in[2];
  const int* valid = (const int*)d_in[3];
  const float* Wq = (const float*)d_in[4];
  const float* Wk = (const float*)d_in[5];
  const float* Wv = (const float*)d_in[6];
  const float* Wo = (const float*)d_in[7];
  float* out = (float*)d_out;

  u16* ws = (u16*)d_ws;
  const long MK = 4096L * 1024;
  const long NK = 1024L * 1024;
  u16* qkvb = ws;              // bf16 Q,K,V  3*MK (dead after proj GEMM)
  u16* wqkv = qkvb + 3 * MK;   // bf16 Wq,Wk,Wv 3*NK (dead after proj GEMM)
  u16* wo = wqkv + 3 * NK;     // bf16 Wo NK
  u16* proj = wo + NK;         // q,k,v projections 3*MK
  u16* ob = proj + 3 * MK;     // attention output MK
  // dead-region reuse after proj GEMM:
  u16* perm = wqkv;                                  // 64*1024 u16 = 128 KB
  u16* partO = qkvb;                                 // 3072 slots*4096 u16 = 25.2 MB (exact fit)
  float* partM = (float*)(wqkv + 64 * 1024);         // 3072*64 f32 = 786 KB
  float* partL = partM + 3072L * 64;                 // 786 KB

  cvt7<<<dim3(2048, 7), 256, 0, stream>>>(Q, K, V, Wq, Wk, Wv, Wo, ws);

  gemm_bt<u16><<<dim3(8, 32, 3), 256, 0, stream>>>(qkvb, wqkv, proj, MK, NK, MK);
  sortperm<<<64, 256, 0, stream>>>(valid, perm);
  attn_kern<<<dim3(48, 64), 256, 0, stream>>>(proj, proj + MK, proj + 2 * MK, valid,
                                              perm, partO, partM, partL);
  merge_kern<<<dim3(16, 64), 256, 0, stream>>>(valid, perm, partO, partM, partL, ob);
  gemm_bt64<<<dim3(16, 64), 256, 0, stream>>>(ob, wo, out);
}

// Round 26
// 133.031 us; speedup vs baseline: 1.1634x; 1.0198x over previous
//
#include <hip/hip_runtime.h>
#include <hip/hip_bf16.h>

typedef short v8s __attribute__((ext_vector_type(8)));
typedef unsigned short v8u __attribute__((ext_vector_type(8)));
typedef float v4f __attribute__((ext_vector_type(4)));
typedef unsigned short u16;

#define LL 1024
#define DD 1024

static __device__ __forceinline__ u16 f2b(float x) {
  __hip_bfloat16 h = __float2bfloat16(x);
  return __builtin_bit_cast(u16, h);
}
static __device__ __forceinline__ float b2f(u16 u) {
  unsigned int x = ((unsigned int)u) << 16;
  return __builtin_bit_cast(float, x);
}

static __device__ __forceinline__ void gload_lds16(const u16* g, u16* l) {
  __builtin_amdgcn_global_load_lds((const __attribute__((address_space(1))) void*)g,
                                   (__attribute__((address_space(3))) void*)l, 16, 0, 0);
}

// ---------------- f32 -> bf16 conversion, ALL 7 tensors in one launch --------
__global__ __launch_bounds__(256) void cvt7(const float* __restrict__ p0,
                                            const float* __restrict__ p1,
                                            const float* __restrict__ p2,
                                            const float* __restrict__ p3,
                                            const float* __restrict__ p4,
                                            const float* __restrict__ p5,
                                            const float* __restrict__ p6,
                                            u16* __restrict__ ws) {
  const long MK = 4096L * 1024, NK = 1024L * 1024;
  const int y = blockIdx.y;
  const float* srcs[7] = {p0, p1, p2, p3, p4, p5, p6};
  const float* src = srcs[y];
  u16* dst = (y < 3) ? ws + (long)y * MK : ws + 3 * MK + (long)(y - 3) * NK;
  const int n8 = (y < 3) ? (int)(MK / 8) : (int)(NK / 8);
  int i = blockIdx.x * 256 + threadIdx.x;
  if (i >= n8) return;
  const float4* p = (const float4*)src + (long)i * 2;
  float4 a = p[0], b = p[1];
  v8u r;
  r[0] = f2b(a.x); r[1] = f2b(a.y); r[2] = f2b(a.z); r[3] = f2b(a.w);
  r[4] = f2b(b.x); r[5] = f2b(b.y); r[6] = f2b(b.z); r[7] = f2b(b.w);
  *((v8u*)dst + i) = r;
}

// ---------------- per-head counting sort of q-rows by effective valid len ----
__global__ __launch_bounds__(256) void sortperm(const int* __restrict__ valid,
                                                u16* __restrict__ perm) {
  __shared__ int hist[1024];
  __shared__ int wsum[4];
  const int bh = blockIdx.x;
  const int tid = threadIdx.x;
  const int* v = valid + bh * 1024;
  for (int i = tid; i < 1024; i += 256) hist[i] = 0;
  __syncthreads();
  for (int i = tid; i < 1024; i += 256) {
    int k = v[i];
    k = (k == 0) ? 1023 : (k - 1);  // bin = eff-1
    atomicAdd(&hist[k], 1);
  }
  __syncthreads();
  const int base = tid * 4;
  int h0 = hist[base], h1 = hist[base + 1], h2 = hist[base + 2], h3 = hist[base + 3];
  int local = h0 + h1 + h2 + h3;
  const int lane = tid & 63, w = tid >> 6;
  int scan = local;
#pragma unroll
  for (int d = 1; d < 64; d <<= 1) {
    int t = __shfl_up(scan, d);
    if (lane >= d) scan += t;
  }
  if (lane == 63) wsum[w] = scan;
  __syncthreads();
  int woff = 0;
  for (int i = 0; i < w; ++i) woff += wsum[i];
  int excl = woff + scan - local;
  hist[base] = excl;
  hist[base + 1] = excl + h0;
  hist[base + 2] = excl + h0 + h1;
  hist[base + 3] = excl + h0 + h1 + h2;
  __syncthreads();
  for (int i = tid; i < 1024; i += 256) {
    int k = v[i];
    k = (k == 0) ? 1023 : (k - 1);
    int pos = atomicAdd(&hist[k], 1);
    perm[bh * 1024 + pos] = (u16)i;
  }
}

// ---------------- C[M,N] = A[M,K] * B[N,K]^T, 128x128 tile (proj GEMM) --------
// T1 XCD-chunked swizzle: dispatch order (x fastest) round-robins XCDs, so the
// 8 n-blocks sharing an A-panel land on 8 DIFFERENT private L2s. Remap
// nf=(flat%8)*32+flat/8 (bijective, 256%8==0) so each XCD owns 4 full m-panels
// -> A-panels + B L2-resident per XCD. Pure index remap: bitwise-identical C.
template <typename OUTT>
__global__ __launch_bounds__(256) void gemm_bt(const u16* __restrict__ A,
                                               const u16* __restrict__ Bw,
                                               OUTT* __restrict__ C,
                                               long za, long zb, long zc) {
  __shared__ u16 As[128 * 64];
  __shared__ u16 Bs[128 * 64];
  A += (long)blockIdx.z * za;
  Bw += (long)blockIdx.z * zb;
  C += (long)blockIdx.z * zc;
  const int flat = blockIdx.y * 8 + blockIdx.x;  // 0..255 in dispatch order
  const int nf = (flat & 7) * 32 + (flat >> 3);  // chunk per XCD
  const int bx = nf & 7, by = nf >> 3;
  const int tid = threadIdx.x;
  const int lane = tid & 63;
  const int l15 = lane & 15, lg = lane >> 4;
  const int wid = tid >> 6;
  const int wm = wid >> 1, wn = wid & 1;
  const long mbase = (long)by * 128;
  const long nbase = (long)bx * 128;

  const u16* ap = A + (mbase + (tid >> 3)) * 1024 + (tid & 7) * 8;
  const u16* bp = Bw + (nbase + (tid >> 3)) * 1024 + (tid & 7) * 8;

  v4f acc[4][4] = {};

  for (int kt = 0; kt < 16; ++kt) {
    __syncthreads();
#pragma unroll
    for (int j = 0; j < 4; ++j) {
      gload_lds16(ap + kt * 64 + j * 32 * 1024, &As[(tid + 256 * j) * 8]);
      gload_lds16(bp + kt * 64 + j * 32 * 1024, &Bs[(tid + 256 * j) * 8]);
    }
    __syncthreads();
#pragma unroll
    for (int kk = 0; kk < 2; ++kk) {
      v8s a[4], b[4];
#pragma unroll
      for (int i = 0; i < 4; ++i)
        a[i] = *(const v8s*)&As[(wm * 64 + i * 16 + l15) * 64 + kk * 32 + lg * 8];
#pragma unroll
      for (int i = 0; i < 4; ++i)
        b[i] = *(const v8s*)&Bs[(wn * 64 + i * 16 + l15) * 64 + kk * 32 + lg * 8];
#pragma unroll
      for (int mi = 0; mi < 4; ++mi)
#pragma unroll
        for (int nj = 0; nj < 4; ++nj)
          acc[mi][nj] = __builtin_amdgcn_mfma_f32_16x16x32_bf16(a[mi], b[nj], acc[mi][nj], 0, 0, 0);
    }
  }
#pragma unroll
  for (int mi = 0; mi < 4; ++mi) {
#pragma unroll
    for (int r = 0; r < 4; ++r) {
      long row = mbase + wm * 64 + mi * 16 + lg * 4 + r;
#pragma unroll
      for (int nj = 0; nj < 4; ++nj) {
        long col = nbase + wn * 64 + nj * 16 + l15;
        if constexpr (__is_same(OUTT, float))
          C[row * 1024 + col] = acc[mi][nj][r];
        else
          C[row * 1024 + col] = f2b(acc[mi][nj][r]);
      }
    }
  }
}

// ---------------- C[M,N] = A[M,K] * B[N,K]^T, 64x64 tile (out GEMM) -----------
// 1024 blocks = 4/CU -> deepest latency-packing (round-23: 135.7us best).
__global__ __launch_bounds__(256) void gemm_bt64(const u16* __restrict__ A,
                                                 const u16* __restrict__ Bw,
                                                 float* __restrict__ C) {
  __shared__ u16 As[64 * 64];
  __shared__ u16 Bs[64 * 64];
  const int tid = threadIdx.x;
  const int lane = tid & 63;
  const int l15 = lane & 15, lg = lane >> 4;
  const int wid = tid >> 6;
  const int wm = wid >> 1, wn = wid & 1;  // wave = 32 rows x 32 cols
  const long mbase = (long)blockIdx.y * 64;
  const long nbase = (long)blockIdx.x * 64;

  const u16* ap = A + (mbase + (tid >> 3)) * 1024 + (tid & 7) * 8;
  const u16* bp = Bw + (nbase + (tid >> 3)) * 1024 + (tid & 7) * 8;

  v4f acc[2][2] = {};

  for (int kt = 0; kt < 16; ++kt) {
    __syncthreads();
#pragma unroll
    for (int j = 0; j < 2; ++j) {
      gload_lds16(ap + kt * 64 + j * 32 * 1024, &As[(tid + 256 * j) * 8]);
      gload_lds16(bp + kt * 64 + j * 32 * 1024, &Bs[(tid + 256 * j) * 8]);
    }
    __syncthreads();
#pragma unroll
    for (int kk = 0; kk < 2; ++kk) {
      v8s a[2], b[2];
#pragma unroll
      for (int i = 0; i < 2; ++i)
        a[i] = *(const v8s*)&As[(wm * 32 + i * 16 + l15) * 64 + kk * 32 + lg * 8];
#pragma unroll
      for (int i = 0; i < 2; ++i)
        b[i] = *(const v8s*)&Bs[(wn * 32 + i * 16 + l15) * 64 + kk * 32 + lg * 8];
#pragma unroll
      for (int mi = 0; mi < 2; ++mi)
#pragma unroll
        for (int nj = 0; nj < 2; ++nj)
          acc[mi][nj] = __builtin_amdgcn_mfma_f32_16x16x32_bf16(a[mi], b[nj], acc[mi][nj], 0, 0, 0);
    }
  }
#pragma unroll
  for (int mi = 0; mi < 2; ++mi) {
#pragma unroll
    for (int r = 0; r < 4; ++r) {
      long row = mbase + wm * 32 + mi * 16 + lg * 4 + r;
#pragma unroll
      for (int nj = 0; nj < 2; ++nj) {
        long col = nbase + wn * 32 + nj * 16 + l15;
        C[row * 1024 + col] = acc[mi][nj][r];
      }
    }
  }
}

// ---------------- fused masked attention, split-K x3 (chunk=6 tiles) ----------
__global__ __launch_bounds__(256) void attn_kern(const u16* __restrict__ qb,
                                                 const u16* __restrict__ kb,
                                                 const u16* __restrict__ vb,
                                                 const int* __restrict__ valid,
                                                 const u16* __restrict__ perm,
                                                 u16* __restrict__ partO,
                                                 float* __restrict__ partM,
                                                 float* __restrict__ partL) {
  __shared__ u16 Ks[64 * 72];       // [key][hd], +8 pad -> no 16-way conflict
  __shared__ u16 Vt[64 * 72];       // [hd][key], transposed for PV B-operand
  __shared__ u16 Ps[4][16 * 72];    // per-wave P tile [q][key]

  const int tid = threadIdx.x;
  const int lane = tid & 63;
  const int wid = tid >> 6;
  const int l15 = lane & 15, lg = lane >> 4;
  const int bh = blockIdx.y;
  const int b = bh >> 4, h = bh & 15;
  const long headoff = ((long)b * LL) * DD + h * 64;
  const int xx = blockIdx.x;
  const int gq = 15 - (xx / 3);    // heaviest sorted group dispatched first
  const int ch = xx % 3;
  const u16* pblk = perm + bh * 1024 + gq * 64;

  const int lastv = valid[bh * LL + pblk[63]];
  const int ntiles = ((lastv == 0 ? LL : lastv) + 63) >> 6;
  const int kt0 = ch * 6;
  const int kt1 = min(ntiles, kt0 + 6);
  if (kt0 >= kt1) return;  // chunk absent for lighter groups
  const int slot = (bh * 16 + gq) * 3 + ch;

  const u16* pp = pblk + wid * 16;

  // Q A-fragments (rows via perm) live in registers for the whole kernel
  const int qrowA = pp[l15];
  v8s qf[2];
#pragma unroll
  for (int ks = 0; ks < 2; ++ks)
    qf[ks] = *(const v8s*)(qb + headoff + (long)qrowA * DD + ks * 32 + lg * 8);

  // per-lane C-frag rows (lg*4+r): raw valid for masking
  int vraw[4];
#pragma unroll
  for (int r = 0; r < 4; ++r) vraw[r] = valid[bh * LL + pp[lg * 4 + r]];

  float mrow[4], lrow[4];
  v4f oacc[4] = {};
#pragma unroll
  for (int r = 0; r < 4; ++r) { mrow[r] = -1e30f; lrow[r] = 0.0f; }

  const int kk = tid & 63;   // staging: key row
  const int qtr = tid >> 6;  // staging: 16-wide hd quarter
  const long stagebase = headoff + (long)kk * DD + qtr * 16;

  // prologue: issue first tile's K/V loads (reg staging, write-late)
  v8s rk0 = *(const v8s*)(kb + stagebase + (long)kt0 * 64 * DD);
  v8s rk1 = *(const v8s*)(kb + stagebase + (long)kt0 * 64 * DD + 8);
  v8s rv0 = *(const v8s*)(vb + stagebase + (long)kt0 * 64 * DD);
  v8s rv1 = *(const v8s*)(vb + stagebase + (long)kt0 * 64 * DD + 8);

  for (int kt = kt0; kt < kt1; ++kt) {
    // ---- barrier A (WAR guard): raw s_barrier, no vmcnt drain.
    __builtin_amdgcn_sched_barrier(0);
    __builtin_amdgcn_s_barrier();
    __builtin_amdgcn_sched_barrier(0);

    // commit staged regs -> LDS (compiler inserts COUNTED vmcnt for rk*/rv*)
    *(v8s*)&Ks[kk * 72 + qtr * 16] = rk0;
    *(v8s*)&Ks[kk * 72 + qtr * 16 + 8] = rk1;
    {
      v8u u0 = __builtin_bit_cast(v8u, rv0);
      v8u u1 = __builtin_bit_cast(v8u, rv1);
#pragma unroll
      for (int j = 0; j < 8; ++j) Vt[(qtr * 16 + j) * 72 + kk] = u0[j];
#pragma unroll
      for (int j = 0; j < 8; ++j) Vt[(qtr * 16 + 8 + j) * 72 + kk] = u1[j];
    }
    // prefetch next tile's K/V; stays in flight across barrier B + compute
    if (kt + 1 < kt1) {
      const long noff = stagebase + (long)(kt + 1) * 64 * DD;
      rk0 = *(const v8s*)(kb + noff);
      rk1 = *(const v8s*)(kb + noff + 8);
      rv0 = *(const v8s*)(vb + noff);
      rv1 = *(const v8s*)(vb + noff + 8);
    }
    // ---- barrier B: ds_writes visible; vmcnt NOT drained.
    asm volatile("s_waitcnt lgkmcnt(0)" ::: "memory");
    __builtin_amdgcn_sched_barrier(0);
    __builtin_amdgcn_s_barrier();
    __builtin_amdgcn_sched_barrier(0);

    // S = Q K^T for 16 q rows x 64 keys
    v4f s[4];
    __builtin_amdgcn_s_setprio(1);
#pragma unroll
    for (int t = 0; t < 4; ++t) {
      v4f z = {};
#pragma unroll
      for (int ks = 0; ks < 2; ++ks) {
        v8s kf = *(const v8s*)&Ks[(t * 16 + l15) * 72 + ks * 32 + lg * 8];
        z = __builtin_amdgcn_mfma_f32_16x16x32_bf16(qf[ks], kf, z, 0, 0, 0);
      }
      s[t] = z;
    }
    __builtin_amdgcn_s_setprio(0);

    // scale into log2 domain + mask (ref semantics: -1e6, col < valid_raw)
    const float SC = 0.18033688f;  // (1/8) * log2(e)
    const int colbase = kt * 64 + l15;
#pragma unroll
    for (int t = 0; t < 4; ++t)
#pragma unroll
      for (int r = 0; r < 4; ++r) {
        float val = s[t][r] * SC;
        s[t][r] = (colbase + t * 16 < vraw[r]) ? val : -1e6f;
      }

    // online softmax (log2 domain) with defer-max: rescale only if max grew >11
    float pm[4];
#pragma unroll
    for (int r = 0; r < 4; ++r)
      pm[r] = fmaxf(fmaxf(s[0][r], s[1][r]), fmaxf(s[2][r], s[3][r]));
#pragma unroll
    for (int d = 1; d < 16; d <<= 1)
#pragma unroll
      for (int r = 0; r < 4; ++r) pm[r] = fmaxf(pm[r], __shfl_xor(pm[r], d));

    bool sk = true;
#pragma unroll
    for (int r = 0; r < 4; ++r) sk = sk && (pm[r] <= mrow[r] + 11.0f);
    if (!__all(sk)) {
#pragma unroll
      for (int r = 0; r < 4; ++r) {
        float mn = fmaxf(mrow[r], pm[r]);
        float sc = __builtin_amdgcn_exp2f(mrow[r] - mn);
        mrow[r] = mn;
        lrow[r] *= sc;
#pragma unroll
        for (int t = 0; t < 4; ++t) oacc[t][r] *= sc;
      }
    }
    float rs[4] = {0.f, 0.f, 0.f, 0.f};
#pragma unroll
    for (int t = 0; t < 4; ++t)
#pragma unroll
      for (int r = 0; r < 4; ++r) {
        float p = __builtin_amdgcn_exp2f(s[t][r] - mrow[r]);
        s[t][r] = p;
        rs[r] += p;
      }
#pragma unroll
    for (int d = 1; d < 16; d <<= 1)
#pragma unroll
      for (int r = 0; r < 4; ++r) rs[r] += __shfl_xor(rs[r], d);
#pragma unroll
    for (int r = 0; r < 4; ++r) lrow[r] += rs[r];

    // P -> bf16 -> per-wave LDS, then consume as MFMA A-operand
#pragma unroll
    for (int t = 0; t < 4; ++t)
#pragma unroll
      for (int r = 0; r < 4; ++r)
        Ps[wid][(lg * 4 + r) * 72 + t * 16 + l15] = f2b(s[t][r]);

    asm volatile("s_waitcnt lgkmcnt(0)" ::: "memory");
    __builtin_amdgcn_sched_barrier(0);

    __builtin_amdgcn_s_setprio(1);
#pragma unroll
    for (int ks = 0; ks < 2; ++ks) {
      v8s pa = *(const v8s*)&Ps[wid][l15 * 72 + ks * 32 + lg * 8];
#pragma unroll
      for (int t = 0; t < 4; ++t) {
        v8s vf = *(const v8s*)&Vt[(t * 16 + l15) * 72 + ks * 32 + lg * 8];
        oacc[t] = __builtin_amdgcn_mfma_f32_16x16x32_bf16(pa, vf, oacc[t], 0, 0, 0);
      }
    }
    __builtin_amdgcn_s_setprio(0);
  }

  // epilogue: write UNNORMALIZED partials (sorted-row order); merge normalizes
  u16* po = partO + (long)slot * 4096;
  float* pmv = partM + slot * 64;
  float* plv = partL + slot * 64;
#pragma unroll
  for (int r = 0; r < 4; ++r) {
    int p = wid * 16 + lg * 4 + r;
    pmv[p] = mrow[r];
    plv[p] = lrow[r];
#pragma unroll
    for (int t = 0; t < 4; ++t)
      po[p * 64 + t * 16 + l15] = f2b(oacc[t][r]);
  }
}

// ---------------- merge the (up to 3) chunk partials per (bh, group) ----------
__global__ __launch_bounds__(256) void merge_kern(const int* __restrict__ valid,
                                                  const u16* __restrict__ perm,
                                                  const u16* __restrict__ partO,
                                                  const float* __restrict__ partM,
                                                  const float* __restrict__ partL,
                                                  u16* __restrict__ ob) {
  const int g = blockIdx.x, bh = blockIdx.y;
  const int b = bh >> 4, h = bh & 15;
  const u16* pblk = perm + bh * 1024 + g * 64;
  const int lastv = valid[bh * LL + pblk[63]];
  const int ntiles = ((lastv == 0 ? LL : lastv) + 63) >> 6;
  const int nch = min(3, (ntiles + 5) / 6);  // chunks present (chunk = 6 tiles)
  const int p = threadIdx.x >> 2;          // sorted row 0..63
  const int q4 = (threadIdx.x & 3) * 16;   // col base
  const int s0 = (bh * 16 + g) * 3;

  float m[3], l[3];
  float M = -1e30f;
  for (int c = 0; c < nch; ++c) {
    m[c] = partM[(s0 + c) * 64 + p];
    l[c] = partL[(s0 + c) * 64 + p];
    M = fmaxf(M, m[c]);
  }
  float w[3], L = 0.0f;
  for (int c = 0; c < nch; ++c) {
    w[c] = __builtin_amdgcn_exp2f(m[c] - M);
    L += l[c] * w[c];
  }
  const float inv = 1.0f / L;

  float acc[16];
#pragma unroll
  for (int j = 0; j < 16; ++j) acc[j] = 0.0f;
  for (int c = 0; c < nch; ++c) {
    const u16* po = partO + (long)(s0 + c) * 4096 + p * 64 + q4;
    v8u x0 = *(const v8u*)po;
    v8u x1 = *(const v8u*)(po + 8);
#pragma unroll
    for (int j = 0; j < 8; ++j) acc[j] += b2f(x0[j]) * w[c];
#pragma unroll
    for (int j = 0; j < 8; ++j) acc[8 + j] += b2f(x1[j]) * w[c];
  }
  const int orow = pblk[p];
  u16* dst = ob + ((long)b * LL + orow) * DD + h * 64 + q4;
#pragma unroll
  for (int j = 0; j < 16; ++j) dst[j] = f2b(acc[j] * inv);
}

// ---------------- launch ------------------------------------------------------
extern "C" void kernel_launch(void* const* d_in, const int* in_sizes, int n_in,
                              void* d_out, int out_size, void* d_ws, size_t ws_size,
                              hipStream_t stream) {
  const float* Q = (const float*)d_in[0];
  const float* K = (const float*)d_in[1];
  const float* V = (const float*)d_in[2];
  const int* valid = (const int*)d_in[3];
  const float* Wq = (const float*)d_in[4];
  const float* Wk = (const float*)d_in[5];
  const float* Wv = (const float*)d_in[6];
  const float* Wo = (const float*)d_in[7];
  float* out = (float*)d_out;

  u16* ws = (u16*)d_ws;
  const long MK = 4096L * 1024;
  const long NK = 1024L * 1024;
  u16* qkvb = ws;              // bf16 Q,K,V  3*MK (dead after proj GEMM)
  u16* wqkv = qkvb + 3 * MK;   // bf16 Wq,Wk,Wv 3*NK (dead after proj GEMM)
  u16* wo = wqkv + 3 * NK;     // bf16 Wo NK
  u16* proj = wo + NK;         // q,k,v projections 3*MK
  u16* ob = proj + 3 * MK;     // attention output MK
  // dead-region reuse after proj GEMM:
  u16* perm = wqkv;                                  // 64*1024 u16 = 128 KB
  u16* partO = qkvb;                                 // 3072 slots*4096 u16 = 25.2 MB (exact fit)
  float* partM = (float*)(wqkv + 64 * 1024);         // 3072*64 f32 = 786 KB
  float* partL = partM + 3072L * 64;                 // 786 KB

  cvt7<<<dim3(2048, 7), 256, 0, stream>>>(Q, K, V, Wq, Wk, Wv, Wo, ws);

  gemm_bt<u16><<<dim3(8, 32, 3), 256, 0, stream>>>(qkvb, wqkv, proj, MK, NK, MK);
  sortperm<<<64, 256, 0, stream>>>(valid, perm);
  attn_kern<<<dim3(48, 64), 256, 0, stream>>>(proj, proj + MK, proj + 2 * MK, valid,
                                              perm, partO, partM, partL);
  merge_kern<<<dim3(16, 64), 256, 0, stream>>>(valid, perm, partO, partM, partL, ob);
  gemm_bt64<<<dim3(16, 64), 256, 0, stream>>>(ob, wo, out);
}

// Round 27
// 132.486 us; speedup vs baseline: 1.1682x; 1.0041x over previous
//
#include <hip/hip_runtime.h>
#include <hip/hip_bf16.h>

typedef short v8s __attribute__((ext_vector_type(8)));
typedef unsigned short v8u __attribute__((ext_vector_type(8)));
typedef float v4f __attribute__((ext_vector_type(4)));
typedef unsigned short u16;

#define LL 1024
#define DD 1024

static __device__ __forceinline__ u16 f2b(float x) {
  __hip_bfloat16 h = __float2bfloat16(x);
  return __builtin_bit_cast(u16, h);
}
static __device__ __forceinline__ float b2f(u16 u) {
  unsigned int x = ((unsigned int)u) << 16;
  return __builtin_bit_cast(float, x);
}

static __device__ __forceinline__ void gload_lds16(const u16* g, u16* l) {
  __builtin_amdgcn_global_load_lds((const __attribute__((address_space(1))) void*)g,
                                   (__attribute__((address_space(3))) void*)l, 16, 0, 0);
}

// ---------------- f32 -> bf16 conversion, ALL 7 tensors in one launch --------
__global__ __launch_bounds__(256) void cvt7(const float* __restrict__ p0,
                                            const float* __restrict__ p1,
                                            const float* __restrict__ p2,
                                            const float* __restrict__ p3,
                                            const float* __restrict__ p4,
                                            const float* __restrict__ p5,
                                            const float* __restrict__ p6,
                                            u16* __restrict__ ws) {
  const long MK = 4096L * 1024, NK = 1024L * 1024;
  const int y = blockIdx.y;
  const float* srcs[7] = {p0, p1, p2, p3, p4, p5, p6};
  const float* src = srcs[y];
  u16* dst = (y < 3) ? ws + (long)y * MK : ws + 3 * MK + (long)(y - 3) * NK;
  const int n8 = (y < 3) ? (int)(MK / 8) : (int)(NK / 8);
  int i = blockIdx.x * 256 + threadIdx.x;
  if (i >= n8) return;
  const float4* p = (const float4*)src + (long)i * 2;
  float4 a = p[0], b = p[1];
  v8u r;
  r[0] = f2b(a.x); r[1] = f2b(a.y); r[2] = f2b(a.z); r[3] = f2b(a.w);
  r[4] = f2b(b.x); r[5] = f2b(b.y); r[6] = f2b(b.z); r[7] = f2b(b.w);
  *((v8u*)dst + i) = r;
}

// ---------------- per-head counting sort of q-rows by effective valid len ----
__global__ __launch_bounds__(256) void sortperm(const int* __restrict__ valid,
                                                u16* __restrict__ perm) {
  __shared__ int hist[1024];
  __shared__ int wsum[4];
  const int bh = blockIdx.x;
  const int tid = threadIdx.x;
  const int* v = valid + bh * 1024;
  for (int i = tid; i < 1024; i += 256) hist[i] = 0;
  __syncthreads();
  for (int i = tid; i < 1024; i += 256) {
    int k = v[i];
    k = (k == 0) ? 1023 : (k - 1);  // bin = eff-1
    atomicAdd(&hist[k], 1);
  }
  __syncthreads();
  const int base = tid * 4;
  int h0 = hist[base], h1 = hist[base + 1], h2 = hist[base + 2], h3 = hist[base + 3];
  int local = h0 + h1 + h2 + h3;
  const int lane = tid & 63, w = tid >> 6;
  int scan = local;
#pragma unroll
  for (int d = 1; d < 64; d <<= 1) {
    int t = __shfl_up(scan, d);
    if (lane >= d) scan += t;
  }
  if (lane == 63) wsum[w] = scan;
  __syncthreads();
  int woff = 0;
  for (int i = 0; i < w; ++i) woff += wsum[i];
  int excl = woff + scan - local;
  hist[base] = excl;
  hist[base + 1] = excl + h0;
  hist[base + 2] = excl + h0 + h1;
  hist[base + 3] = excl + h0 + h1 + h2;
  __syncthreads();
  for (int i = tid; i < 1024; i += 256) {
    int k = v[i];
    k = (k == 0) ? 1023 : (k - 1);
    int pos = atomicAdd(&hist[k], 1);
    perm[bh * 1024 + pos] = (u16)i;
  }
}

// ---------------- C[M,N] = A[M,K] * B[N,K]^T, 128x128 tile (proj GEMM) --------
// T1 XCD-chunked swizzle (validated round 26: -2.7us): each XCD owns 4 full
// m-panels x 8 n-blocks -> A-panels + B L2-resident per XCD. Bitwise-identical.
template <typename OUTT>
__global__ __launch_bounds__(256) void gemm_bt(const u16* __restrict__ A,
                                               const u16* __restrict__ Bw,
                                               OUTT* __restrict__ C,
                                               long za, long zb, long zc) {
  __shared__ u16 As[128 * 64];
  __shared__ u16 Bs[128 * 64];
  A += (long)blockIdx.z * za;
  Bw += (long)blockIdx.z * zb;
  C += (long)blockIdx.z * zc;
  const int flat = blockIdx.y * 8 + blockIdx.x;  // 0..255 in dispatch order
  const int nf = (flat & 7) * 32 + (flat >> 3);  // chunk per XCD
  const int bx = nf & 7, by = nf >> 3;
  const int tid = threadIdx.x;
  const int lane = tid & 63;
  const int l15 = lane & 15, lg = lane >> 4;
  const int wid = tid >> 6;
  const int wm = wid >> 1, wn = wid & 1;
  const long mbase = (long)by * 128;
  const long nbase = (long)bx * 128;

  const u16* ap = A + (mbase + (tid >> 3)) * 1024 + (tid & 7) * 8;
  const u16* bp = Bw + (nbase + (tid >> 3)) * 1024 + (tid & 7) * 8;

  v4f acc[4][4] = {};

  for (int kt = 0; kt < 16; ++kt) {
    __syncthreads();
#pragma unroll
    for (int j = 0; j < 4; ++j) {
      gload_lds16(ap + kt * 64 + j * 32 * 1024, &As[(tid + 256 * j) * 8]);
      gload_lds16(bp + kt * 64 + j * 32 * 1024, &Bs[(tid + 256 * j) * 8]);
    }
    __syncthreads();
#pragma unroll
    for (int kk = 0; kk < 2; ++kk) {
      v8s a[4], b[4];
#pragma unroll
      for (int i = 0; i < 4; ++i)
        a[i] = *(const v8s*)&As[(wm * 64 + i * 16 + l15) * 64 + kk * 32 + lg * 8];
#pragma unroll
      for (int i = 0; i < 4; ++i)
        b[i] = *(const v8s*)&Bs[(wn * 64 + i * 16 + l15) * 64 + kk * 32 + lg * 8];
#pragma unroll
      for (int mi = 0; mi < 4; ++mi)
#pragma unroll
        for (int nj = 0; nj < 4; ++nj)
          acc[mi][nj] = __builtin_amdgcn_mfma_f32_16x16x32_bf16(a[mi], b[nj], acc[mi][nj], 0, 0, 0);
    }
  }
#pragma unroll
  for (int mi = 0; mi < 4; ++mi) {
#pragma unroll
    for (int r = 0; r < 4; ++r) {
      long row = mbase + wm * 64 + mi * 16 + lg * 4 + r;
#pragma unroll
      for (int nj = 0; nj < 4; ++nj) {
        long col = nbase + wn * 64 + nj * 16 + l15;
        if constexpr (__is_same(OUTT, float))
          C[row * 1024 + col] = acc[mi][nj][r];
        else
          C[row * 1024 + col] = f2b(acc[mi][nj][r]);
      }
    }
  }
}

// ---------------- C[M,N] = A[M,K] * B[N,K]^T, 64x64 tile (out GEMM) -----------
// 1024 blocks = 4/CU latency-packing + T1 XCD-chunked swizzle (mechanism
// validated on proj GEMM, round 26): each XCD owns 8 full m-panels x 16
// n-blocks -> A-panels (512KB) + Wo (2MB) L2-resident. Bitwise-identical.
__global__ __launch_bounds__(256) void gemm_bt64(const u16* __restrict__ A,
                                                 const u16* __restrict__ Bw,
                                                 float* __restrict__ C) {
  __shared__ u16 As[64 * 64];
  __shared__ u16 Bs[64 * 64];
  const int flat = blockIdx.y * 16 + blockIdx.x;   // 0..1023 in dispatch order
  const int nf = (flat & 7) * 128 + (flat >> 3);   // chunk per XCD (1024%8==0)
  const int bx = nf & 15, by = nf >> 4;
  const int tid = threadIdx.x;
  const int lane = tid & 63;
  const int l15 = lane & 15, lg = lane >> 4;
  const int wid = tid >> 6;
  const int wm = wid >> 1, wn = wid & 1;  // wave = 32 rows x 32 cols
  const long mbase = (long)by * 64;
  const long nbase = (long)bx * 64;

  const u16* ap = A + (mbase + (tid >> 3)) * 1024 + (tid & 7) * 8;
  const u16* bp = Bw + (nbase + (tid >> 3)) * 1024 + (tid & 7) * 8;

  v4f acc[2][2] = {};

  for (int kt = 0; kt < 16; ++kt) {
    __syncthreads();
#pragma unroll
    for (int j = 0; j < 2; ++j) {
      gload_lds16(ap + kt * 64 + j * 32 * 1024, &As[(tid + 256 * j) * 8]);
      gload_lds16(bp + kt * 64 + j * 32 * 1024, &Bs[(tid + 256 * j) * 8]);
    }
    __syncthreads();
#pragma unroll
    for (int kk = 0; kk < 2; ++kk) {
      v8s a[2], b[2];
#pragma unroll
      for (int i = 0; i < 2; ++i)
        a[i] = *(const v8s*)&As[(wm * 32 + i * 16 + l15) * 64 + kk * 32 + lg * 8];
#pragma unroll
      for (int i = 0; i < 2; ++i)
        b[i] = *(const v8s*)&Bs[(wn * 32 + i * 16 + l15) * 64 + kk * 32 + lg * 8];
#pragma unroll
      for (int mi = 0; mi < 2; ++mi)
#pragma unroll
        for (int nj = 0; nj < 2; ++nj)
          acc[mi][nj] = __builtin_amdgcn_mfma_f32_16x16x32_bf16(a[mi], b[nj], acc[mi][nj], 0, 0, 0);
    }
  }
#pragma unroll
  for (int mi = 0; mi < 2; ++mi) {
#pragma unroll
    for (int r = 0; r < 4; ++r) {
      long row = mbase + wm * 32 + mi * 16 + lg * 4 + r;
#pragma unroll
      for (int nj = 0; nj < 2; ++nj) {
        long col = nbase + wn * 32 + nj * 16 + l15;
        C[row * 1024 + col] = acc[mi][nj][r];
      }
    }
  }
}

// ---------------- fused masked attention, split-K x3 (chunk=6 tiles) ----------
__global__ __launch_bounds__(256) void attn_kern(const u16* __restrict__ qb,
                                                 const u16* __restrict__ kb,
                                                 const u16* __restrict__ vb,
                                                 const int* __restrict__ valid,
                                                 const u16* __restrict__ perm,
                                                 u16* __restrict__ partO,
                                                 float* __restrict__ partM,
                                                 float* __restrict__ partL) {
  __shared__ u16 Ks[64 * 72];       // [key][hd], +8 pad -> no 16-way conflict
  __shared__ u16 Vt[64 * 72];       // [hd][key], transposed for PV B-operand
  __shared__ u16 Ps[4][16 * 72];    // per-wave P tile [q][key]

  const int tid = threadIdx.x;
  const int lane = tid & 63;
  const int wid = tid >> 6;
  const int l15 = lane & 15, lg = lane >> 4;
  const int bh = blockIdx.y;
  const int b = bh >> 4, h = bh & 15;
  const long headoff = ((long)b * LL) * DD + h * 64;
  const int xx = blockIdx.x;
  const int gq = 15 - (xx / 3);    // heaviest sorted group dispatched first
  const int ch = xx % 3;
  const u16* pblk = perm + bh * 1024 + gq * 64;

  const int lastv = valid[bh * LL + pblk[63]];
  const int ntiles = ((lastv == 0 ? LL : lastv) + 63) >> 6;
  const int kt0 = ch * 6;
  const int kt1 = min(ntiles, kt0 + 6);
  if (kt0 >= kt1) return;  // chunk absent for lighter groups
  const int slot = (bh * 16 + gq) * 3 + ch;

  const u16* pp = pblk + wid * 16;

  // Q A-fragments (rows via perm) live in registers for the whole kernel
  const int qrowA = pp[l15];
  v8s qf[2];
#pragma unroll
  for (int ks = 0; ks < 2; ++ks)
    qf[ks] = *(const v8s*)(qb + headoff + (long)qrowA * DD + ks * 32 + lg * 8);

  // per-lane C-frag rows (lg*4+r): raw valid for masking
  int vraw[4];
#pragma unroll
  for (int r = 0; r < 4; ++r) vraw[r] = valid[bh * LL + pp[lg * 4 + r]];

  float mrow[4], lrow[4];
  v4f oacc[4] = {};
#pragma unroll
  for (int r = 0; r < 4; ++r) { mrow[r] = -1e30f; lrow[r] = 0.0f; }

  const int kk = tid & 63;   // staging: key row
  const int qtr = tid >> 6;  // staging: 16-wide hd quarter
  const long stagebase = headoff + (long)kk * DD + qtr * 16;

  // prologue: issue first tile's K/V loads (reg staging, write-late)
  v8s rk0 = *(const v8s*)(kb + stagebase + (long)kt0 * 64 * DD);
  v8s rk1 = *(const v8s*)(kb + stagebase + (long)kt0 * 64 * DD + 8);
  v8s rv0 = *(const v8s*)(vb + stagebase + (long)kt0 * 64 * DD);
  v8s rv1 = *(const v8s*)(vb + stagebase + (long)kt0 * 64 * DD + 8);

  for (int kt = kt0; kt < kt1; ++kt) {
    // ---- barrier A (WAR guard): raw s_barrier, no vmcnt drain.
    __builtin_amdgcn_sched_barrier(0);
    __builtin_amdgcn_s_barrier();
    __builtin_amdgcn_sched_barrier(0);

    // commit staged regs -> LDS (compiler inserts COUNTED vmcnt for rk*/rv*)
    *(v8s*)&Ks[kk * 72 + qtr * 16] = rk0;
    *(v8s*)&Ks[kk * 72 + qtr * 16 + 8] = rk1;
    {
      v8u u0 = __builtin_bit_cast(v8u, rv0);
      v8u u1 = __builtin_bit_cast(v8u, rv1);
#pragma unroll
      for (int j = 0; j < 8; ++j) Vt[(qtr * 16 + j) * 72 + kk] = u0[j];
#pragma unroll
      for (int j = 0; j < 8; ++j) Vt[(qtr * 16 + 8 + j) * 72 + kk] = u1[j];
    }
    // prefetch next tile's K/V; stays in flight across barrier B + compute
    if (kt + 1 < kt1) {
      const long noff = stagebase + (long)(kt + 1) * 64 * DD;
      rk0 = *(const v8s*)(kb + noff);
      rk1 = *(const v8s*)(kb + noff + 8);
      rv0 = *(const v8s*)(vb + noff);
      rv1 = *(const v8s*)(vb + noff + 8);
    }
    // ---- barrier B: ds_writes visible; vmcnt NOT drained.
    asm volatile("s_waitcnt lgkmcnt(0)" ::: "memory");
    __builtin_amdgcn_sched_barrier(0);
    __builtin_amdgcn_s_barrier();
    __builtin_amdgcn_sched_barrier(0);

    // S = Q K^T for 16 q rows x 64 keys
    v4f s[4];
    __builtin_amdgcn_s_setprio(1);
#pragma unroll
    for (int t = 0; t < 4; ++t) {
      v4f z = {};
#pragma unroll
      for (int ks = 0; ks < 2; ++ks) {
        v8s kf = *(const v8s*)&Ks[(t * 16 + l15) * 72 + ks * 32 + lg * 8];
        z = __builtin_amdgcn_mfma_f32_16x16x32_bf16(qf[ks], kf, z, 0, 0, 0);
      }
      s[t] = z;
    }
    __builtin_amdgcn_s_setprio(0);

    // scale into log2 domain + mask (ref semantics: -1e6, col < valid_raw)
    const float SC = 0.18033688f;  // (1/8) * log2(e)
    const int colbase = kt * 64 + l15;
#pragma unroll
    for (int t = 0; t < 4; ++t)
#pragma unroll
      for (int r = 0; r < 4; ++r) {
        float val = s[t][r] * SC;
        s[t][r] = (colbase + t * 16 < vraw[r]) ? val : -1e6f;
      }

    // online softmax (log2 domain) with defer-max: rescale only if max grew >11
    float pm[4];
#pragma unroll
    for (int r = 0; r < 4; ++r)
      pm[r] = fmaxf(fmaxf(s[0][r], s[1][r]), fmaxf(s[2][r], s[3][r]));
#pragma unroll
    for (int d = 1; d < 16; d <<= 1)
#pragma unroll
      for (int r = 0; r < 4; ++r) pm[r] = fmaxf(pm[r], __shfl_xor(pm[r], d));

    bool sk = true;
#pragma unroll
    for (int r = 0; r < 4; ++r) sk = sk && (pm[r] <= mrow[r] + 11.0f);
    if (!__all(sk)) {
#pragma unroll
      for (int r = 0; r < 4; ++r) {
        float mn = fmaxf(mrow[r], pm[r]);
        float sc = __builtin_amdgcn_exp2f(mrow[r] - mn);
        mrow[r] = mn;
        lrow[r] *= sc;
#pragma unroll
        for (int t = 0; t < 4; ++t) oacc[t][r] *= sc;
      }
    }
    float rs[4] = {0.f, 0.f, 0.f, 0.f};
#pragma unroll
    for (int t = 0; t < 4; ++t)
#pragma unroll
      for (int r = 0; r < 4; ++r) {
        float p = __builtin_amdgcn_exp2f(s[t][r] - mrow[r]);
        s[t][r] = p;
        rs[r] += p;
      }
#pragma unroll
    for (int d = 1; d < 16; d <<= 1)
#pragma unroll
      for (int r = 0; r < 4; ++r) rs[r] += __shfl_xor(rs[r], d);
#pragma unroll
    for (int r = 0; r < 4; ++r) lrow[r] += rs[r];

    // P -> bf16 -> per-wave LDS, then consume as MFMA A-operand
#pragma unroll
    for (int t = 0; t < 4; ++t)
#pragma unroll
      for (int r = 0; r < 4; ++r)
        Ps[wid][(lg * 4 + r) * 72 + t * 16 + l15] = f2b(s[t][r]);

    asm volatile("s_waitcnt lgkmcnt(0)" ::: "memory");
    __builtin_amdgcn_sched_barrier(0);

    __builtin_amdgcn_s_setprio(1);
#pragma unroll
    for (int ks = 0; ks < 2; ++ks) {
      v8s pa = *(const v8s*)&Ps[wid][l15 * 72 + ks * 32 + lg * 8];
#pragma unroll
      for (int t = 0; t < 4; ++t) {
        v8s vf = *(const v8s*)&Vt[(t * 16 + l15) * 72 + ks * 32 + lg * 8];
        oacc[t] = __builtin_amdgcn_mfma_f32_16x16x32_bf16(pa, vf, oacc[t], 0, 0, 0);
      }
    }
    __builtin_amdgcn_s_setprio(0);
  }

  // epilogue: write UNNORMALIZED partials (sorted-row order); merge normalizes
  u16* po = partO + (long)slot * 4096;
  float* pmv = partM + slot * 64;
  float* plv = partL + slot * 64;
#pragma unroll
  for (int r = 0; r < 4; ++r) {
    int p = wid * 16 + lg * 4 + r;
    pmv[p] = mrow[r];
    plv[p] = lrow[r];
#pragma unroll
    for (int t = 0; t < 4; ++t)
      po[p * 64 + t * 16 + l15] = f2b(oacc[t][r]);
  }
}

// ---------------- merge the (up to 3) chunk partials per (bh, group) ----------
__global__ __launch_bounds__(256) void merge_kern(const int* __restrict__ valid,
                                                  const u16* __restrict__ perm,
                                                  const u16* __restrict__ partO,
                                                  const float* __restrict__ partM,
                                                  const float* __restrict__ partL,
                                                  u16* __restrict__ ob) {
  const int g = blockIdx.x, bh = blockIdx.y;
  const int b = bh >> 4, h = bh & 15;
  const u16* pblk = perm + bh * 1024 + g * 64;
  const int lastv = valid[bh * LL + pblk[63]];
  const int ntiles = ((lastv == 0 ? LL : lastv) + 63) >> 6;
  const int nch = min(3, (ntiles + 5) / 6);  // chunks present (chunk = 6 tiles)
  const int p = threadIdx.x >> 2;          // sorted row 0..63
  const int q4 = (threadIdx.x & 3) * 16;   // col base
  const int s0 = (bh * 16 + g) * 3;

  float m[3], l[3];
  float M = -1e30f;
  for (int c = 0; c < nch; ++c) {
    m[c] = partM[(s0 + c) * 64 + p];
    l[c] = partL[(s0 + c) * 64 + p];
    M = fmaxf(M, m[c]);
  }
  float w[3], L = 0.0f;
  for (int c = 0; c < nch; ++c) {
    w[c] = __builtin_amdgcn_exp2f(m[c] - M);
    L += l[c] * w[c];
  }
  const float inv = 1.0f / L;

  float acc[16];
#pragma unroll
  for (int j = 0; j < 16; ++j) acc[j] = 0.0f;
  for (int c = 0; c < nch; ++c) {
    const u16* po = partO + (long)(s0 + c) * 4096 + p * 64 + q4;
    v8u x0 = *(const v8u*)po;
    v8u x1 = *(const v8u*)(po + 8);
#pragma unroll
    for (int j = 0; j < 8; ++j) acc[j] += b2f(x0[j]) * w[c];
#pragma unroll
    for (int j = 0; j < 8; ++j) acc[8 + j] += b2f(x1[j]) * w[c];
  }
  const int orow = pblk[p];
  u16* dst = ob + ((long)b * LL + orow) * DD + h * 64 + q4;
#pragma unroll
  for (int j = 0; j < 16; ++j) dst[j] = f2b(acc[j] * inv);
}

// ---------------- launch ------------------------------------------------------
extern "C" void kernel_launch(void* const* d_in, const int* in_sizes, int n_in,
                              void* d_out, int out_size, void* d_ws, size_t ws_size,
                              hipStream_t stream) {
  const float* Q = (const float*)d_in[0];
  const float* K = (const float*)d_in[1];
  const float* V = (const float*)d_in[2];
  const int* valid = (const int*)d_in[3];
  const float* Wq = (const float*)d_in[4];
  const float* Wk = (const float*)d_in[5];
  const float* Wv = (const float*)d_in[6];
  const float* Wo = (const float*)d_in[7];
  float* out = (float*)d_out;

  u16* ws = (u16*)d_ws;
  const long MK = 4096L * 1024;
  const long NK = 1024L * 1024;
  u16* qkvb = ws;              // bf16 Q,K,V  3*MK (dead after proj GEMM)
  u16* wqkv = qkvb + 3 * MK;   // bf16 Wq,Wk,Wv 3*NK (dead after proj GEMM)
  u16* wo = wqkv + 3 * NK;     // bf16 Wo NK
  u16* proj = wo + NK;         // q,k,v projections 3*MK
  u16* ob = proj + 3 * MK;     // attention output MK
  // dead-region reuse after proj GEMM:
  u16* perm = wqkv;                                  // 64*1024 u16 = 128 KB
  u16* partO = qkvb;                                 // 3072 slots*4096 u16 = 25.2 MB (exact fit)
  float* partM = (float*)(wqkv + 64 * 1024);         // 3072*64 f32 = 786 KB
  float* partL = partM + 3072L * 64;                 // 786 KB

  cvt7<<<dim3(2048, 7), 256, 0, stream>>>(Q, K, V, Wq, Wk, Wv, Wo, ws);

  gemm_bt<u16><<<dim3(8, 32, 3), 256, 0, stream>>>(qkvb, wqkv, proj, MK, NK, MK);
  sortperm<<<64, 256, 0, stream>>>(valid, perm);
  attn_kern<<<dim3(48, 64), 256, 0, stream>>>(proj, proj + MK, proj + 2 * MK, valid,
                                              perm, partO, partM, partL);
  merge_kern<<<dim3(16, 64), 256, 0, stream>>>(valid, perm, partO, partM, partL, ob);
  gemm_bt64<<<dim3(16, 64), 256, 0, stream>>>(ob, wo, out);
}

// Round 28
// 132.422 us; speedup vs baseline: 1.1688x; 1.0005x over previous
//
#include <hip/hip_runtime.h>
#include <hip/hip_bf16.h>

typedef short v8s __attribute__((ext_vector_type(8)));
typedef unsigned short v8u __attribute__((ext_vector_type(8)));
typedef float v4f __attribute__((ext_vector_type(4)));
typedef unsigned short u16;

#define LL 1024
#define DD 1024

static __device__ __forceinline__ u16 f2b(float x) {
  __hip_bfloat16 h = __float2bfloat16(x);
  return __builtin_bit_cast(u16, h);
}
static __device__ __forceinline__ float b2f(u16 u) {
  unsigned int x = ((unsigned int)u) << 16;
  return __builtin_bit_cast(float, x);
}

static __device__ __forceinline__ void gload_lds16(const u16* g, u16* l) {
  __builtin_amdgcn_global_load_lds((const __attribute__((address_space(1))) void*)g,
                                   (__attribute__((address_space(3))) void*)l, 16, 0, 0);
}

// ---------------- f32 -> bf16 conversion, ALL 7 tensors in one launch --------
__global__ __launch_bounds__(256) void cvt7(const float* __restrict__ p0,
                                            const float* __restrict__ p1,
                                            const float* __restrict__ p2,
                                            const float* __restrict__ p3,
                                            const float* __restrict__ p4,
                                            const float* __restrict__ p5,
                                            const float* __restrict__ p6,
                                            u16* __restrict__ ws) {
  const long MK = 4096L * 1024, NK = 1024L * 1024;
  const int y = blockIdx.y;
  const float* srcs[7] = {p0, p1, p2, p3, p4, p5, p6};
  const float* src = srcs[y];
  u16* dst = (y < 3) ? ws + (long)y * MK : ws + 3 * MK + (long)(y - 3) * NK;
  const int n8 = (y < 3) ? (int)(MK / 8) : (int)(NK / 8);
  int i = blockIdx.x * 256 + threadIdx.x;
  if (i >= n8) return;
  const float4* p = (const float4*)src + (long)i * 2;
  float4 a = p[0], b = p[1];
  v8u r;
  r[0] = f2b(a.x); r[1] = f2b(a.y); r[2] = f2b(a.z); r[3] = f2b(a.w);
  r[4] = f2b(b.x); r[5] = f2b(b.y); r[6] = f2b(b.z); r[7] = f2b(b.w);
  *((v8u*)dst + i) = r;
}

// ---------------- per-head counting sort of q-rows by effective valid len ----
__global__ __launch_bounds__(256) void sortperm(const int* __restrict__ valid,
                                                u16* __restrict__ perm) {
  __shared__ int hist[1024];
  __shared__ int wsum[4];
  const int bh = blockIdx.x;
  const int tid = threadIdx.x;
  const int* v = valid + bh * 1024;
  for (int i = tid; i < 1024; i += 256) hist[i] = 0;
  __syncthreads();
  for (int i = tid; i < 1024; i += 256) {
    int k = v[i];
    k = (k == 0) ? 1023 : (k - 1);  // bin = eff-1
    atomicAdd(&hist[k], 1);
  }
  __syncthreads();
  const int base = tid * 4;
  int h0 = hist[base], h1 = hist[base + 1], h2 = hist[base + 2], h3 = hist[base + 3];
  int local = h0 + h1 + h2 + h3;
  const int lane = tid & 63, w = tid >> 6;
  int scan = local;
#pragma unroll
  for (int d = 1; d < 64; d <<= 1) {
    int t = __shfl_up(scan, d);
    if (lane >= d) scan += t;
  }
  if (lane == 63) wsum[w] = scan;
  __syncthreads();
  int woff = 0;
  for (int i = 0; i < w; ++i) woff += wsum[i];
  int excl = woff + scan - local;
  hist[base] = excl;
  hist[base + 1] = excl + h0;
  hist[base + 2] = excl + h0 + h1;
  hist[base + 3] = excl + h0 + h1 + h2;
  __syncthreads();
  for (int i = tid; i < 1024; i += 256) {
    int k = v[i];
    k = (k == 0) ? 1023 : (k - 1);
    int pos = atomicAdd(&hist[k], 1);
    perm[bh * 1024 + pos] = (u16)i;
  }
}

// ---------------- C[M,N] = A[M,K] * B[N,K]^T, 128x128 tile (proj GEMM) --------
// T1 XCD-chunked swizzle (validated round 26: -2.7us): each XCD owns 4 full
// m-panels x 8 n-blocks -> A-panels + B L2-resident per XCD. Bitwise-identical.
template <typename OUTT>
__global__ __launch_bounds__(256) void gemm_bt(const u16* __restrict__ A,
                                               const u16* __restrict__ Bw,
                                               OUTT* __restrict__ C,
                                               long za, long zb, long zc) {
  __shared__ u16 As[128 * 64];
  __shared__ u16 Bs[128 * 64];
  A += (long)blockIdx.z * za;
  Bw += (long)blockIdx.z * zb;
  C += (long)blockIdx.z * zc;
  const int flat = blockIdx.y * 8 + blockIdx.x;  // 0..255 in dispatch order
  const int nf = (flat & 7) * 32 + (flat >> 3);  // chunk per XCD
  const int bx = nf & 7, by = nf >> 3;
  const int tid = threadIdx.x;
  const int lane = tid & 63;
  const int l15 = lane & 15, lg = lane >> 4;
  const int wid = tid >> 6;
  const int wm = wid >> 1, wn = wid & 1;
  const long mbase = (long)by * 128;
  const long nbase = (long)bx * 128;

  const u16* ap = A + (mbase + (tid >> 3)) * 1024 + (tid & 7) * 8;
  const u16* bp = Bw + (nbase + (tid >> 3)) * 1024 + (tid & 7) * 8;

  v4f acc[4][4] = {};

  for (int kt = 0; kt < 16; ++kt) {
    __syncthreads();
#pragma unroll
    for (int j = 0; j < 4; ++j) {
      gload_lds16(ap + kt * 64 + j * 32 * 1024, &As[(tid + 256 * j) * 8]);
      gload_lds16(bp + kt * 64 + j * 32 * 1024, &Bs[(tid + 256 * j) * 8]);
    }
    __syncthreads();
#pragma unroll
    for (int kk = 0; kk < 2; ++kk) {
      v8s a[4], b[4];
#pragma unroll
      for (int i = 0; i < 4; ++i)
        a[i] = *(const v8s*)&As[(wm * 64 + i * 16 + l15) * 64 + kk * 32 + lg * 8];
#pragma unroll
      for (int i = 0; i < 4; ++i)
        b[i] = *(const v8s*)&Bs[(wn * 64 + i * 16 + l15) * 64 + kk * 32 + lg * 8];
#pragma unroll
      for (int mi = 0; mi < 4; ++mi)
#pragma unroll
        for (int nj = 0; nj < 4; ++nj)
          acc[mi][nj] = __builtin_amdgcn_mfma_f32_16x16x32_bf16(a[mi], b[nj], acc[mi][nj], 0, 0, 0);
    }
  }
#pragma unroll
  for (int mi = 0; mi < 4; ++mi) {
#pragma unroll
    for (int r = 0; r < 4; ++r) {
      long row = mbase + wm * 64 + mi * 16 + lg * 4 + r;
#pragma unroll
      for (int nj = 0; nj < 4; ++nj) {
        long col = nbase + wn * 64 + nj * 16 + l15;
        if constexpr (__is_same(OUTT, float))
          C[row * 1024 + col] = acc[mi][nj][r];
        else
          C[row * 1024 + col] = f2b(acc[mi][nj][r]);
      }
    }
  }
}

// ---------------- C[M,N] = A[M,K] * B[N,K]^T, 64x64 tile (out GEMM) -----------
// 1024 blocks = 4/CU latency-packing + T1 XCD-chunked swizzle (round 27).
__global__ __launch_bounds__(256) void gemm_bt64(const u16* __restrict__ A,
                                                 const u16* __restrict__ Bw,
                                                 float* __restrict__ C) {
  __shared__ u16 As[64 * 64];
  __shared__ u16 Bs[64 * 64];
  const int flat = blockIdx.y * 16 + blockIdx.x;   // 0..1023 in dispatch order
  const int nf = (flat & 7) * 128 + (flat >> 3);   // chunk per XCD (1024%8==0)
  const int bx = nf & 15, by = nf >> 4;
  const int tid = threadIdx.x;
  const int lane = tid & 63;
  const int l15 = lane & 15, lg = lane >> 4;
  const int wid = tid >> 6;
  const int wm = wid >> 1, wn = wid & 1;  // wave = 32 rows x 32 cols
  const long mbase = (long)by * 64;
  const long nbase = (long)bx * 64;

  const u16* ap = A + (mbase + (tid >> 3)) * 1024 + (tid & 7) * 8;
  const u16* bp = Bw + (nbase + (tid >> 3)) * 1024 + (tid & 7) * 8;

  v4f acc[2][2] = {};

  for (int kt = 0; kt < 16; ++kt) {
    __syncthreads();
#pragma unroll
    for (int j = 0; j < 2; ++j) {
      gload_lds16(ap + kt * 64 + j * 32 * 1024, &As[(tid + 256 * j) * 8]);
      gload_lds16(bp + kt * 64 + j * 32 * 1024, &Bs[(tid + 256 * j) * 8]);
    }
    __syncthreads();
#pragma unroll
    for (int kk = 0; kk < 2; ++kk) {
      v8s a[2], b[2];
#pragma unroll
      for (int i = 0; i < 2; ++i)
        a[i] = *(const v8s*)&As[(wm * 32 + i * 16 + l15) * 64 + kk * 32 + lg * 8];
#pragma unroll
      for (int i = 0; i < 2; ++i)
        b[i] = *(const v8s*)&Bs[(wn * 32 + i * 16 + l15) * 64 + kk * 32 + lg * 8];
#pragma unroll
      for (int mi = 0; mi < 2; ++mi)
#pragma unroll
        for (int nj = 0; nj < 2; ++nj)
          acc[mi][nj] = __builtin_amdgcn_mfma_f32_16x16x32_bf16(a[mi], b[nj], acc[mi][nj], 0, 0, 0);
    }
  }
#pragma unroll
  for (int mi = 0; mi < 2; ++mi) {
#pragma unroll
    for (int r = 0; r < 4; ++r) {
      long row = mbase + wm * 32 + mi * 16 + lg * 4 + r;
#pragma unroll
      for (int nj = 0; nj < 2; ++nj) {
        long col = nbase + wn * 32 + nj * 16 + l15;
        C[row * 1024 + col] = acc[mi][nj][r];
      }
    }
  }
}

// ---------------- fused masked attention, split-K x3 (chunk=6 tiles) ----------
__global__ __launch_bounds__(256) void attn_kern(const u16* __restrict__ qb,
                                                 const u16* __restrict__ kb,
                                                 const u16* __restrict__ vb,
                                                 const int* __restrict__ valid,
                                                 const u16* __restrict__ perm,
                                                 u16* __restrict__ partO,
                                                 float* __restrict__ partM,
                                                 float* __restrict__ partL) {
  __shared__ u16 Ks[64 * 72];       // [key][hd], +8 pad -> no 16-way conflict
  __shared__ u16 Vt[64 * 72];       // [hd][key], transposed for PV B-operand
  __shared__ u16 Ps[4][16 * 72];    // per-wave P tile [q][key]

  const int tid = threadIdx.x;
  const int lane = tid & 63;
  const int wid = tid >> 6;
  const int l15 = lane & 15, lg = lane >> 4;
  const int bh = blockIdx.y;
  const int b = bh >> 4, h = bh & 15;
  const long headoff = ((long)b * LL) * DD + h * 64;
  const int xx = blockIdx.x;
  const int gq = 15 - (xx / 3);    // heaviest sorted group dispatched first
  const int ch = xx % 3;
  const u16* pblk = perm + bh * 1024 + gq * 64;

  const int lastv = valid[bh * LL + pblk[63]];
  const int ntiles = ((lastv == 0 ? LL : lastv) + 63) >> 6;
  const int kt0 = ch * 6;
  const int kt1 = min(ntiles, kt0 + 6);
  if (kt0 >= kt1) return;  // chunk absent for lighter groups
  const int slot = (bh * 16 + gq) * 3 + ch;

  const u16* pp = pblk + wid * 16;

  // Q A-fragments (rows via perm) live in registers for the whole kernel
  const int qrowA = pp[l15];
  v8s qf[2];
#pragma unroll
  for (int ks = 0; ks < 2; ++ks)
    qf[ks] = *(const v8s*)(qb + headoff + (long)qrowA * DD + ks * 32 + lg * 8);

  // per-lane C-frag rows (lg*4+r): raw valid for masking
  int vraw[4];
#pragma unroll
  for (int r = 0; r < 4; ++r) vraw[r] = valid[bh * LL + pp[lg * 4 + r]];

  float mrow[4], lrow[4];
  v4f oacc[4] = {};
#pragma unroll
  for (int r = 0; r < 4; ++r) { mrow[r] = -1e30f; lrow[r] = 0.0f; }

  const int kk = tid & 63;   // staging: key row
  const int qtr = tid >> 6;  // staging: 16-wide hd quarter
  const long stagebase = headoff + (long)kk * DD + qtr * 16;

  // prologue: issue first tile's K/V loads (reg staging, write-late)
  v8s rk0 = *(const v8s*)(kb + stagebase + (long)kt0 * 64 * DD);
  v8s rk1 = *(const v8s*)(kb + stagebase + (long)kt0 * 64 * DD + 8);
  v8s rv0 = *(const v8s*)(vb + stagebase + (long)kt0 * 64 * DD);
  v8s rv1 = *(const v8s*)(vb + stagebase + (long)kt0 * 64 * DD + 8);

  for (int kt = kt0; kt < kt1; ++kt) {
    // ---- barrier A (WAR guard): raw s_barrier, no vmcnt drain.
    __builtin_amdgcn_sched_barrier(0);
    __builtin_amdgcn_s_barrier();
    __builtin_amdgcn_sched_barrier(0);

    // commit staged regs -> LDS (compiler inserts COUNTED vmcnt for rk*/rv*)
    *(v8s*)&Ks[kk * 72 + qtr * 16] = rk0;
    *(v8s*)&Ks[kk * 72 + qtr * 16 + 8] = rk1;
    {
      v8u u0 = __builtin_bit_cast(v8u, rv0);
      v8u u1 = __builtin_bit_cast(v8u, rv1);
#pragma unroll
      for (int j = 0; j < 8; ++j) Vt[(qtr * 16 + j) * 72 + kk] = u0[j];
#pragma unroll
      for (int j = 0; j < 8; ++j) Vt[(qtr * 16 + 8 + j) * 72 + kk] = u1[j];
    }
    // prefetch next tile's K/V; stays in flight across barrier B + compute
    if (kt + 1 < kt1) {
      const long noff = stagebase + (long)(kt + 1) * 64 * DD;
      rk0 = *(const v8s*)(kb + noff);
      rk1 = *(const v8s*)(kb + noff + 8);
      rv0 = *(const v8s*)(vb + noff);
      rv1 = *(const v8s*)(vb + noff + 8);
    }
    // ---- barrier B: ds_writes visible; vmcnt NOT drained.
    asm volatile("s_waitcnt lgkmcnt(0)" ::: "memory");
    __builtin_amdgcn_sched_barrier(0);
    __builtin_amdgcn_s_barrier();
    __builtin_amdgcn_sched_barrier(0);

    // S = Q K^T for 16 q rows x 64 keys
    v4f s[4];
    __builtin_amdgcn_s_setprio(1);
#pragma unroll
    for (int t = 0; t < 4; ++t) {
      v4f z = {};
#pragma unroll
      for (int ks = 0; ks < 2; ++ks) {
        v8s kf = *(const v8s*)&Ks[(t * 16 + l15) * 72 + ks * 32 + lg * 8];
        z = __builtin_amdgcn_mfma_f32_16x16x32_bf16(qf[ks], kf, z, 0, 0, 0);
      }
      s[t] = z;
    }
    __builtin_amdgcn_s_setprio(0);

    // scale into log2 domain + mask (ref semantics: -1e6, col < valid_raw)
    const float SC = 0.18033688f;  // (1/8) * log2(e)
    const int colbase = kt * 64 + l15;
#pragma unroll
    for (int t = 0; t < 4; ++t)
#pragma unroll
      for (int r = 0; r < 4; ++r) {
        float val = s[t][r] * SC;
        s[t][r] = (colbase + t * 16 < vraw[r]) ? val : -1e6f;
      }

    // online softmax (log2 domain) with defer-max: rescale only if max grew >11
    float pm[4];
#pragma unroll
    for (int r = 0; r < 4; ++r)
      pm[r] = fmaxf(fmaxf(s[0][r], s[1][r]), fmaxf(s[2][r], s[3][r]));
#pragma unroll
    for (int d = 1; d < 16; d <<= 1)
#pragma unroll
      for (int r = 0; r < 4; ++r) pm[r] = fmaxf(pm[r], __shfl_xor(pm[r], d));

    bool sk = true;
#pragma unroll
    for (int r = 0; r < 4; ++r) sk = sk && (pm[r] <= mrow[r] + 11.0f);
    if (!__all(sk)) {
#pragma unroll
      for (int r = 0; r < 4; ++r) {
        float mn = fmaxf(mrow[r], pm[r]);
        float sc = __builtin_amdgcn_exp2f(mrow[r] - mn);
        mrow[r] = mn;
        lrow[r] *= sc;
#pragma unroll
        for (int t = 0; t < 4; ++t) oacc[t][r] *= sc;
      }
    }
    float rs[4] = {0.f, 0.f, 0.f, 0.f};
#pragma unroll
    for (int t = 0; t < 4; ++t)
#pragma unroll
      for (int r = 0; r < 4; ++r) {
        float p = __builtin_amdgcn_exp2f(s[t][r] - mrow[r]);
        s[t][r] = p;
        rs[r] += p;
      }
#pragma unroll
    for (int d = 1; d < 16; d <<= 1)
#pragma unroll
      for (int r = 0; r < 4; ++r) rs[r] += __shfl_xor(rs[r], d);
#pragma unroll
    for (int r = 0; r < 4; ++r) lrow[r] += rs[r];

    // P -> bf16 -> per-wave LDS, then consume as MFMA A-operand
#pragma unroll
    for (int t = 0; t < 4; ++t)
#pragma unroll
      for (int r = 0; r < 4; ++r)
        Ps[wid][(lg * 4 + r) * 72 + t * 16 + l15] = f2b(s[t][r]);

    asm volatile("s_waitcnt lgkmcnt(0)" ::: "memory");
    __builtin_amdgcn_sched_barrier(0);

    __builtin_amdgcn_s_setprio(1);
#pragma unroll
    for (int ks = 0; ks < 2; ++ks) {
      v8s pa = *(const v8s*)&Ps[wid][l15 * 72 + ks * 32 + lg * 8];
#pragma unroll
      for (int t = 0; t < 4; ++t) {
        v8s vf = *(const v8s*)&Vt[(t * 16 + l15) * 72 + ks * 32 + lg * 8];
        oacc[t] = __builtin_amdgcn_mfma_f32_16x16x32_bf16(pa, vf, oacc[t], 0, 0, 0);
      }
    }
    __builtin_amdgcn_s_setprio(0);
  }

  // epilogue: write UNNORMALIZED partials (sorted-row order); merge normalizes
  u16* po = partO + (long)slot * 4096;
  float* pmv = partM + slot * 64;
  float* plv = partL + slot * 64;
#pragma unroll
  for (int r = 0; r < 4; ++r) {
    int p = wid * 16 + lg * 4 + r;
    pmv[p] = mrow[r];
    plv[p] = lrow[r];
#pragma unroll
    for (int t = 0; t < 4; ++t)
      po[p * 64 + t * 16 + l15] = f2b(oacc[t][r]);
  }
}

// ---------------- merge the (up to 3) chunk partials per (bh, group) ----------
__global__ __launch_bounds__(256) void merge_kern(const int* __restrict__ valid,
                                                  const u16* __restrict__ perm,
                                                  const u16* __restrict__ partO,
                                                  const float* __restrict__ partM,
                                                  const float* __restrict__ partL,
                                                  u16* __restrict__ ob) {
  const int g = blockIdx.x, bh = blockIdx.y;
  const int b = bh >> 4, h = bh & 15;
  const u16* pblk = perm + bh * 1024 + g * 64;
  const int lastv = valid[bh * LL + pblk[63]];
  const int ntiles = ((lastv == 0 ? LL : lastv) + 63) >> 6;
  const int nch = min(3, (ntiles + 5) / 6);  // chunks present (chunk = 6 tiles)
  const int p = threadIdx.x >> 2;          // sorted row 0..63
  const int q4 = (threadIdx.x & 3) * 16;   // col base
  const int s0 = (bh * 16 + g) * 3;

  float m[3], l[3];
  float M = -1e30f;
  for (int c = 0; c < nch; ++c) {
    m[c] = partM[(s0 + c) * 64 + p];
    l[c] = partL[(s0 + c) * 64 + p];
    M = fmaxf(M, m[c]);
  }
  float w[3], L = 0.0f;
  for (int c = 0; c < nch; ++c) {
    w[c] = __builtin_amdgcn_exp2f(m[c] - M);
    L += l[c] * w[c];
  }
  const float inv = 1.0f / L;

  float acc[16];
#pragma unroll
  for (int j = 0; j < 16; ++j) acc[j] = 0.0f;
  for (int c = 0; c < nch; ++c) {
    const u16* po = partO + (long)(s0 + c) * 4096 + p * 64 + q4;
    v8u x0 = *(const v8u*)po;
    v8u x1 = *(const v8u*)(po + 8);
#pragma unroll
    for (int j = 0; j < 8; ++j) acc[j] += b2f(x0[j]) * w[c];
#pragma unroll
    for (int j = 0; j < 8; ++j) acc[8 + j] += b2f(x1[j]) * w[c];
  }
  const int orow = pblk[p];
  u16* dst = ob + ((long)b * LL + orow) * DD + h * 64 + q4;
#pragma unroll
  for (int j = 0; j < 16; ++j) dst[j] = f2b(acc[j] * inv);
}

// ---------------- launch ------------------------------------------------------
extern "C" void kernel_launch(void* const* d_in, const int* in_sizes, int n_in,
                              void* d_out, int out_size, void* d_ws, size_t ws_size,
                              hipStream_t stream) {
  const float* Q = (const float*)d_in[0];
  const float* K = (const float*)d_in[1];
  const float* V = (const float*)d_in[2];
  const int* valid = (const int*)d_in[3];
  const float* Wq = (const float*)d_in[4];
  const float* Wk = (const float*)d_in[5];
  const float* Wv = (const float*)d_in[6];
  const float* Wo = (const float*)d_in[7];
  float* out = (float*)d_out;

  u16* ws = (u16*)d_ws;
  const long MK = 4096L * 1024;
  const long NK = 1024L * 1024;
  u16* qkvb = ws;              // bf16 Q,K,V  3*MK (dead after proj GEMM)
  u16* wqkv = qkvb + 3 * MK;   // bf16 Wq,Wk,Wv 3*NK (dead after proj GEMM)
  u16* wo = wqkv + 3 * NK;     // bf16 Wo NK
  u16* proj = wo + NK;         // q,k,v projections 3*MK
  u16* ob = proj + 3 * MK;     // attention output MK
  // dead-region reuse after proj GEMM:
  u16* perm = wqkv;                                  // 64*1024 u16 = 128 KB
  u16* partO = qkvb;                                 // 3072 slots*4096 u16 = 25.2 MB (exact fit)
  float* partM = (float*)(wqkv + 64 * 1024);         // 3072*64 f32 = 786 KB
  float* partL = partM + 3072L * 64;                 // 786 KB

  cvt7<<<dim3(2048, 7), 256, 0, stream>>>(Q, K, V, Wq, Wk, Wv, Wo, ws);

  gemm_bt<u16><<<dim3(8, 32, 3), 256, 0, stream>>>(qkvb, wqkv, proj, MK, NK, MK);
  sortperm<<<64, 256, 0, stream>>>(valid, perm);
  attn_kern<<<dim3(48, 64), 256, 0, stream>>>(proj, proj + MK, proj + 2 * MK, valid,
                                              perm, partO, partM, partL);
  merge_kern<<<dim3(16, 64), 256, 0, stream>>>(valid, perm, partO, partM, partL, ob);
  gemm_bt64<<<dim3(16, 64), 256, 0, stream>>>(ob, wo, out);
}

// Round 29
// 132.353 us; speedup vs baseline: 1.1694x; 1.0005x over previous
//
#include <hip/hip_runtime.h>
#include <hip/hip_bf16.h>

typedef short v8s __attribute__((ext_vector_type(8)));
typedef unsigned short v8u __attribute__((ext_vector_type(8)));
typedef float v4f __attribute__((ext_vector_type(4)));
typedef unsigned short u16;

#define LL 1024
#define DD 1024

static __device__ __forceinline__ u16 f2b(float x) {
  __hip_bfloat16 h = __float2bfloat16(x);
  return __builtin_bit_cast(u16, h);
}
static __device__ __forceinline__ float b2f(u16 u) {
  unsigned int x = ((unsigned int)u) << 16;
  return __builtin_bit_cast(float, x);
}

static __device__ __forceinline__ void gload_lds16(const u16* g, u16* l) {
  __builtin_amdgcn_global_load_lds((const __attribute__((address_space(1))) void*)g,
                                   (__attribute__((address_space(3))) void*)l, 16, 0, 0);
}

// ---------------- f32 -> bf16 conversion, ALL 7 tensors in one launch --------
__global__ __launch_bounds__(256) void cvt7(const float* __restrict__ p0,
                                            const float* __restrict__ p1,
                                            const float* __restrict__ p2,
                                            const float* __restrict__ p3,
                                            const float* __restrict__ p4,
                                            const float* __restrict__ p5,
                                            const float* __restrict__ p6,
                                            u16* __restrict__ ws) {
  const long MK = 4096L * 1024, NK = 1024L * 1024;
  const int y = blockIdx.y;
  const float* srcs[7] = {p0, p1, p2, p3, p4, p5, p6};
  const float* src = srcs[y];
  u16* dst = (y < 3) ? ws + (long)y * MK : ws + 3 * MK + (long)(y - 3) * NK;
  const int n8 = (y < 3) ? (int)(MK / 8) : (int)(NK / 8);
  int i = blockIdx.x * 256 + threadIdx.x;
  if (i >= n8) return;
  const float4* p = (const float4*)src + (long)i * 2;
  float4 a = p[0], b = p[1];
  v8u r;
  r[0] = f2b(a.x); r[1] = f2b(a.y); r[2] = f2b(a.z); r[3] = f2b(a.w);
  r[4] = f2b(b.x); r[5] = f2b(b.y); r[6] = f2b(b.z); r[7] = f2b(b.w);
  *((v8u*)dst + i) = r;
}

// ---------------- per-head counting sort of q-rows by effective valid len ----
__global__ __launch_bounds__(256) void sortperm(const int* __restrict__ valid,
                                                u16* __restrict__ perm) {
  __shared__ int hist[1024];
  __shared__ int wsum[4];
  const int bh = blockIdx.x;
  const int tid = threadIdx.x;
  const int* v = valid + bh * 1024;
  for (int i = tid; i < 1024; i += 256) hist[i] = 0;
  __syncthreads();
  for (int i = tid; i < 1024; i += 256) {
    int k = v[i];
    k = (k == 0) ? 1023 : (k - 1);  // bin = eff-1
    atomicAdd(&hist[k], 1);
  }
  __syncthreads();
  const int base = tid * 4;
  int h0 = hist[base], h1 = hist[base + 1], h2 = hist[base + 2], h3 = hist[base + 3];
  int local = h0 + h1 + h2 + h3;
  const int lane = tid & 63, w = tid >> 6;
  int scan = local;
#pragma unroll
  for (int d = 1; d < 64; d <<= 1) {
    int t = __shfl_up(scan, d);
    if (lane >= d) scan += t;
  }
  if (lane == 63) wsum[w] = scan;
  __syncthreads();
  int woff = 0;
  for (int i = 0; i < w; ++i) woff += wsum[i];
  int excl = woff + scan - local;
  hist[base] = excl;
  hist[base + 1] = excl + h0;
  hist[base + 2] = excl + h0 + h1;
  hist[base + 3] = excl + h0 + h1 + h2;
  __syncthreads();
  for (int i = tid; i < 1024; i += 256) {
    int k = v[i];
    k = (k == 0) ? 1023 : (k - 1);
    int pos = atomicAdd(&hist[k], 1);
    perm[bh * 1024 + pos] = (u16)i;
  }
}

// ---------------- C[M,N] = A[M,K] * B[N,K]^T, 128x128 tile (proj GEMM) --------
// T1 XCD-chunked swizzle (validated round 26: -2.7us): each XCD owns 4 full
// m-panels x 8 n-blocks -> A-panels + B L2-resident per XCD. Bitwise-identical.
template <typename OUTT>
__global__ __launch_bounds__(256) void gemm_bt(const u16* __restrict__ A,
                                               const u16* __restrict__ Bw,
                                               OUTT* __restrict__ C,
                                               long za, long zb, long zc) {
  __shared__ u16 As[128 * 64];
  __shared__ u16 Bs[128 * 64];
  A += (long)blockIdx.z * za;
  Bw += (long)blockIdx.z * zb;
  C += (long)blockIdx.z * zc;
  const int flat = blockIdx.y * 8 + blockIdx.x;  // 0..255 in dispatch order
  const int nf = (flat & 7) * 32 + (flat >> 3);  // chunk per XCD
  const int bx = nf & 7, by = nf >> 3;
  const int tid = threadIdx.x;
  const int lane = tid & 63;
  const int l15 = lane & 15, lg = lane >> 4;
  const int wid = tid >> 6;
  const int wm = wid >> 1, wn = wid & 1;
  const long mbase = (long)by * 128;
  const long nbase = (long)bx * 128;

  const u16* ap = A + (mbase + (tid >> 3)) * 1024 + (tid & 7) * 8;
  const u16* bp = Bw + (nbase + (tid >> 3)) * 1024 + (tid & 7) * 8;

  v4f acc[4][4] = {};

  for (int kt = 0; kt < 16; ++kt) {
    __syncthreads();
#pragma unroll
    for (int j = 0; j < 4; ++j) {
      gload_lds16(ap + kt * 64 + j * 32 * 1024, &As[(tid + 256 * j) * 8]);
      gload_lds16(bp + kt * 64 + j * 32 * 1024, &Bs[(tid + 256 * j) * 8]);
    }
    __syncthreads();
#pragma unroll
    for (int kk = 0; kk < 2; ++kk) {
      v8s a[4], b[4];
#pragma unroll
      for (int i = 0; i < 4; ++i)
        a[i] = *(const v8s*)&As[(wm * 64 + i * 16 + l15) * 64 + kk * 32 + lg * 8];
#pragma unroll
      for (int i = 0; i < 4; ++i)
        b[i] = *(const v8s*)&Bs[(wn * 64 + i * 16 + l15) * 64 + kk * 32 + lg * 8];
#pragma unroll
      for (int mi = 0; mi < 4; ++mi)
#pragma unroll
        for (int nj = 0; nj < 4; ++nj)
          acc[mi][nj] = __builtin_amdgcn_mfma_f32_16x16x32_bf16(a[mi], b[nj], acc[mi][nj], 0, 0, 0);
    }
  }
#pragma unroll
  for (int mi = 0; mi < 4; ++mi) {
#pragma unroll
    for (int r = 0; r < 4; ++r) {
      long row = mbase + wm * 64 + mi * 16 + lg * 4 + r;
#pragma unroll
      for (int nj = 0; nj < 4; ++nj) {
        long col = nbase + wn * 64 + nj * 16 + l15;
        if constexpr (__is_same(OUTT, float))
          C[row * 1024 + col] = acc[mi][nj][r];
        else
          C[row * 1024 + col] = f2b(acc[mi][nj][r]);
      }
    }
  }
}

// ---------------- C[M,N] = A[M,K] * B[N,K]^T, 64x64 tile (out GEMM) -----------
// 1024 blocks = 4/CU latency-packing + T1 XCD-chunked swizzle (round 27).
__global__ __launch_bounds__(256) void gemm_bt64(const u16* __restrict__ A,
                                                 const u16* __restrict__ Bw,
                                                 float* __restrict__ C) {
  __shared__ u16 As[64 * 64];
  __shared__ u16 Bs[64 * 64];
  const int flat = blockIdx.y * 16 + blockIdx.x;   // 0..1023 in dispatch order
  const int nf = (flat & 7) * 128 + (flat >> 3);   // chunk per XCD (1024%8==0)
  const int bx = nf & 15, by = nf >> 4;
  const int tid = threadIdx.x;
  const int lane = tid & 63;
  const int l15 = lane & 15, lg = lane >> 4;
  const int wid = tid >> 6;
  const int wm = wid >> 1, wn = wid & 1;  // wave = 32 rows x 32 cols
  const long mbase = (long)by * 64;
  const long nbase = (long)bx * 64;

  const u16* ap = A + (mbase + (tid >> 3)) * 1024 + (tid & 7) * 8;
  const u16* bp = Bw + (nbase + (tid >> 3)) * 1024 + (tid & 7) * 8;

  v4f acc[2][2] = {};

  for (int kt = 0; kt < 16; ++kt) {
    __syncthreads();
#pragma unroll
    for (int j = 0; j < 2; ++j) {
      gload_lds16(ap + kt * 64 + j * 32 * 1024, &As[(tid + 256 * j) * 8]);
      gload_lds16(bp + kt * 64 + j * 32 * 1024, &Bs[(tid + 256 * j) * 8]);
    }
    __syncthreads();
#pragma unroll
    for (int kk = 0; kk < 2; ++kk) {
      v8s a[2], b[2];
#pragma unroll
      for (int i = 0; i < 2; ++i)
        a[i] = *(const v8s*)&As[(wm * 32 + i * 16 + l15) * 64 + kk * 32 + lg * 8];
#pragma unroll
      for (int i = 0; i < 2; ++i)
        b[i] = *(const v8s*)&Bs[(wn * 32 + i * 16 + l15) * 64 + kk * 32 + lg * 8];
#pragma unroll
      for (int mi = 0; mi < 2; ++mi)
#pragma unroll
        for (int nj = 0; nj < 2; ++nj)
          acc[mi][nj] = __builtin_amdgcn_mfma_f32_16x16x32_bf16(a[mi], b[nj], acc[mi][nj], 0, 0, 0);
    }
  }
#pragma unroll
  for (int mi = 0; mi < 2; ++mi) {
#pragma unroll
    for (int r = 0; r < 4; ++r) {
      long row = mbase + wm * 32 + mi * 16 + lg * 4 + r;
#pragma unroll
      for (int nj = 0; nj < 2; ++nj) {
        long col = nbase + wn * 32 + nj * 16 + l15;
        C[row * 1024 + col] = acc[mi][nj][r];
      }
    }
  }
}

// ---------------- fused masked attention, split-K x3 (chunk=6 tiles) ----------
__global__ __launch_bounds__(256) void attn_kern(const u16* __restrict__ qb,
                                                 const u16* __restrict__ kb,
                                                 const u16* __restrict__ vb,
                                                 const int* __restrict__ valid,
                                                 const u16* __restrict__ perm,
                                                 u16* __restrict__ partO,
                                                 float* __restrict__ partM,
                                                 float* __restrict__ partL) {
  __shared__ u16 Ks[64 * 72];       // [key][hd], +8 pad -> no 16-way conflict
  __shared__ u16 Vt[64 * 72];       // [hd][key], transposed for PV B-operand
  __shared__ u16 Ps[4][16 * 72];    // per-wave P tile [q][key]

  const int tid = threadIdx.x;
  const int lane = tid & 63;
  const int wid = tid >> 6;
  const int l15 = lane & 15, lg = lane >> 4;
  const int bh = blockIdx.y;
  const int b = bh >> 4, h = bh & 15;
  const long headoff = ((long)b * LL) * DD + h * 64;
  const int xx = blockIdx.x;
  const int gq = 15 - (xx / 3);    // heaviest sorted group dispatched first
  const int ch = xx % 3;
  const u16* pblk = perm + bh * 1024 + gq * 64;

  const int lastv = valid[bh * LL + pblk[63]];
  const int ntiles = ((lastv == 0 ? LL : lastv) + 63) >> 6;
  const int kt0 = ch * 6;
  const int kt1 = min(ntiles, kt0 + 6);
  if (kt0 >= kt1) return;  // chunk absent for lighter groups
  const int slot = (bh * 16 + gq) * 3 + ch;

  const u16* pp = pblk + wid * 16;

  // Q A-fragments (rows via perm) live in registers for the whole kernel
  const int qrowA = pp[l15];
  v8s qf[2];
#pragma unroll
  for (int ks = 0; ks < 2; ++ks)
    qf[ks] = *(const v8s*)(qb + headoff + (long)qrowA * DD + ks * 32 + lg * 8);

  // per-lane C-frag rows (lg*4+r): raw valid for masking
  int vraw[4];
#pragma unroll
  for (int r = 0; r < 4; ++r) vraw[r] = valid[bh * LL + pp[lg * 4 + r]];

  float mrow[4], lrow[4];
  v4f oacc[4] = {};
#pragma unroll
  for (int r = 0; r < 4; ++r) { mrow[r] = -1e30f; lrow[r] = 0.0f; }

  const int kk = tid & 63;   // staging: key row
  const int qtr = tid >> 6;  // staging: 16-wide hd quarter
  const long stagebase = headoff + (long)kk * DD + qtr * 16;

  // prologue: issue first tile's K/V loads (reg staging, write-late)
  v8s rk0 = *(const v8s*)(kb + stagebase + (long)kt0 * 64 * DD);
  v8s rk1 = *(const v8s*)(kb + stagebase + (long)kt0 * 64 * DD + 8);
  v8s rv0 = *(const v8s*)(vb + stagebase + (long)kt0 * 64 * DD);
  v8s rv1 = *(const v8s*)(vb + stagebase + (long)kt0 * 64 * DD + 8);

  for (int kt = kt0; kt < kt1; ++kt) {
    // ---- barrier A (WAR guard): raw s_barrier, no vmcnt drain.
    __builtin_amdgcn_sched_barrier(0);
    __builtin_amdgcn_s_barrier();
    __builtin_amdgcn_sched_barrier(0);

    // commit staged regs -> LDS (compiler inserts COUNTED vmcnt for rk*/rv*)
    *(v8s*)&Ks[kk * 72 + qtr * 16] = rk0;
    *(v8s*)&Ks[kk * 72 + qtr * 16 + 8] = rk1;
    {
      v8u u0 = __builtin_bit_cast(v8u, rv0);
      v8u u1 = __builtin_bit_cast(v8u, rv1);
#pragma unroll
      for (int j = 0; j < 8; ++j) Vt[(qtr * 16 + j) * 72 + kk] = u0[j];
#pragma unroll
      for (int j = 0; j < 8; ++j) Vt[(qtr * 16 + 8 + j) * 72 + kk] = u1[j];
    }
    // prefetch next tile's K/V; stays in flight across barrier B + compute
    if (kt + 1 < kt1) {
      const long noff = stagebase + (long)(kt + 1) * 64 * DD;
      rk0 = *(const v8s*)(kb + noff);
      rk1 = *(const v8s*)(kb + noff + 8);
      rv0 = *(const v8s*)(vb + noff);
      rv1 = *(const v8s*)(vb + noff + 8);
    }
    // ---- barrier B: ds_writes visible; vmcnt NOT drained.
    asm volatile("s_waitcnt lgkmcnt(0)" ::: "memory");
    __builtin_amdgcn_sched_barrier(0);
    __builtin_amdgcn_s_barrier();
    __builtin_amdgcn_sched_barrier(0);

    // S = Q K^T for 16 q rows x 64 keys
    v4f s[4];
    __builtin_amdgcn_s_setprio(1);
#pragma unroll
    for (int t = 0; t < 4; ++t) {
      v4f z = {};
#pragma unroll
      for (int ks = 0; ks < 2; ++ks) {
        v8s kf = *(const v8s*)&Ks[(t * 16 + l15) * 72 + ks * 32 + lg * 8];
        z = __builtin_amdgcn_mfma_f32_16x16x32_bf16(qf[ks], kf, z, 0, 0, 0);
      }
      s[t] = z;
    }
    __builtin_amdgcn_s_setprio(0);

    // scale into log2 domain + mask (ref semantics: -1e6, col < valid_raw)
    const float SC = 0.18033688f;  // (1/8) * log2(e)
    const int colbase = kt * 64 + l15;
#pragma unroll
    for (int t = 0; t < 4; ++t)
#pragma unroll
      for (int r = 0; r < 4; ++r) {
        float val = s[t][r] * SC;
        s[t][r] = (colbase + t * 16 < vraw[r]) ? val : -1e6f;
      }

    // online softmax (log2 domain) with defer-max: rescale only if max grew >11
    float pm[4];
#pragma unroll
    for (int r = 0; r < 4; ++r)
      pm[r] = fmaxf(fmaxf(s[0][r], s[1][r]), fmaxf(s[2][r], s[3][r]));
#pragma unroll
    for (int d = 1; d < 16; d <<= 1)
#pragma unroll
      for (int r = 0; r < 4; ++r) pm[r] = fmaxf(pm[r], __shfl_xor(pm[r], d));

    bool sk = true;
#pragma unroll
    for (int r = 0; r < 4; ++r) sk = sk && (pm[r] <= mrow[r] + 11.0f);
    if (!__all(sk)) {
#pragma unroll
      for (int r = 0; r < 4; ++r) {
        float mn = fmaxf(mrow[r], pm[r]);
        float sc = __builtin_amdgcn_exp2f(mrow[r] - mn);
        mrow[r] = mn;
        lrow[r] *= sc;
#pragma unroll
        for (int t = 0; t < 4; ++t) oacc[t][r] *= sc;
      }
    }
    float rs[4] = {0.f, 0.f, 0.f, 0.f};
#pragma unroll
    for (int t = 0; t < 4; ++t)
#pragma unroll
      for (int r = 0; r < 4; ++r) {
        float p = __builtin_amdgcn_exp2f(s[t][r] - mrow[r]);
        s[t][r] = p;
        rs[r] += p;
      }
#pragma unroll
    for (int d = 1; d < 16; d <<= 1)
#pragma unroll
      for (int r = 0; r < 4; ++r) rs[r] += __shfl_xor(rs[r], d);
#pragma unroll
    for (int r = 0; r < 4; ++r) lrow[r] += rs[r];

    // P -> bf16 -> per-wave LDS, then consume as MFMA A-operand
#pragma unroll
    for (int t = 0; t < 4; ++t)
#pragma unroll
      for (int r = 0; r < 4; ++r)
        Ps[wid][(lg * 4 + r) * 72 + t * 16 + l15] = f2b(s[t][r]);

    asm volatile("s_waitcnt lgkmcnt(0)" ::: "memory");
    __builtin_amdgcn_sched_barrier(0);

    __builtin_amdgcn_s_setprio(1);
#pragma unroll
    for (int ks = 0; ks < 2; ++ks) {
      v8s pa = *(const v8s*)&Ps[wid][l15 * 72 + ks * 32 + lg * 8];
#pragma unroll
      for (int t = 0; t < 4; ++t) {
        v8s vf = *(const v8s*)&Vt[(t * 16 + l15) * 72 + ks * 32 + lg * 8];
        oacc[t] = __builtin_amdgcn_mfma_f32_16x16x32_bf16(pa, vf, oacc[t], 0, 0, 0);
      }
    }
    __builtin_amdgcn_s_setprio(0);
  }

  // epilogue: write UNNORMALIZED partials (sorted-row order); merge normalizes
  u16* po = partO + (long)slot * 4096;
  float* pmv = partM + slot * 64;
  float* plv = partL + slot * 64;
#pragma unroll
  for (int r = 0; r < 4; ++r) {
    int p = wid * 16 + lg * 4 + r;
    pmv[p] = mrow[r];
    plv[p] = lrow[r];
#pragma unroll
    for (int t = 0; t < 4; ++t)
      po[p * 64 + t * 16 + l15] = f2b(oacc[t][r]);
  }
}

// ---------------- merge the (up to 3) chunk partials per (bh, group) ----------
__global__ __launch_bounds__(256) void merge_kern(const int* __restrict__ valid,
                                                  const u16* __restrict__ perm,
                                                  const u16* __restrict__ partO,
                                                  const float* __restrict__ partM,
                                                  const float* __restrict__ partL,
                                                  u16* __restrict__ ob) {
  const int g = blockIdx.x, bh = blockIdx.y;
  const int b = bh >> 4, h = bh & 15;
  const u16* pblk = perm + bh * 1024 + g * 64;
  const int lastv = valid[bh * LL + pblk[63]];
  const int ntiles = ((lastv == 0 ? LL : lastv) + 63) >> 6;
  const int nch = min(3, (ntiles + 5) / 6);  // chunks present (chunk = 6 tiles)
  const int p = threadIdx.x >> 2;          // sorted row 0..63
  const int q4 = (threadIdx.x & 3) * 16;   // col base
  const int s0 = (bh * 16 + g) * 3;

  float m[3], l[3];
  float M = -1e30f;
  for (int c = 0; c < nch; ++c) {
    m[c] = partM[(s0 + c) * 64 + p];
    l[c] = partL[(s0 + c) * 64 + p];
    M = fmaxf(M, m[c]);
  }
  float w[3], L = 0.0f;
  for (int c = 0; c < nch; ++c) {
    w[c] = __builtin_amdgcn_exp2f(m[c] - M);
    L += l[c] * w[c];
  }
  const float inv = 1.0f / L;

  float acc[16];
#pragma unroll
  for (int j = 0; j < 16; ++j) acc[j] = 0.0f;
  for (int c = 0; c < nch; ++c) {
    const u16* po = partO + (long)(s0 + c) * 4096 + p * 64 + q4;
    v8u x0 = *(const v8u*)po;
    v8u x1 = *(const v8u*)(po + 8);
#pragma unroll
    for (int j = 0; j < 8; ++j) acc[j] += b2f(x0[j]) * w[c];
#pragma unroll
    for (int j = 0; j < 8; ++j) acc[8 + j] += b2f(x1[j]) * w[c];
  }
  const int orow = pblk[p];
  u16* dst = ob + ((long)b * LL + orow) * DD + h * 64 + q4;
#pragma unroll
  for (int j = 0; j < 16; ++j) dst[j] = f2b(acc[j] * inv);
}

// ---------------- launch ------------------------------------------------------
extern "C" void kernel_launch(void* const* d_in, const int* in_sizes, int n_in,
                              void* d_out, int out_size, void* d_ws, size_t ws_size,
                              hipStream_t stream) {
  const float* Q = (const float*)d_in[0];
  const float* K = (const float*)d_in[1];
  const float* V = (const float*)d_in[2];
  const int* valid = (const int*)d_in[3];
  const float* Wq = (const float*)d_in[4];
  const float* Wk = (const float*)d_in[5];
  const float* Wv = (const float*)d_in[6];
  const float* Wo = (const float*)d_in[7];
  float* out = (float*)d_out;

  u16* ws = (u16*)d_ws;
  const long MK = 4096L * 1024;
  const long NK = 1024L * 1024;
  u16* qkvb = ws;              // bf16 Q,K,V  3*MK (dead after proj GEMM)
  u16* wqkv = qkvb + 3 * MK;   // bf16 Wq,Wk,Wv 3*NK (dead after proj GEMM)
  u16* wo = wqkv + 3 * NK;     // bf16 Wo NK
  u16* proj = wo + NK;         // q,k,v projections 3*MK
  u16* ob = proj + 3 * MK;     // attention output MK
  // dead-region reuse after proj GEMM:
  u16* perm = wqkv;                                  // 64*1024 u16 = 128 KB
  u16* partO = qkvb;                                 // 3072 slots*4096 u16 = 25.2 MB (exact fit)
  float* partM = (float*)(wqkv + 64 * 1024);         // 3072*64 f32 = 786 KB
  float* partL = partM + 3072L * 64;                 // 786 KB

  cvt7<<<dim3(2048, 7), 256, 0, stream>>>(Q, K, V, Wq, Wk, Wv, Wo, ws);

  gemm_bt<u16><<<dim3(8, 32, 3), 256, 0, stream>>>(qkvb, wqkv, proj, MK, NK, MK);
  sortperm<<<64, 256, 0, stream>>>(valid, perm);
  attn_kern<<<dim3(48, 64), 256, 0, stream>>>(proj, proj + MK, proj + 2 * MK, valid,
                                              perm, partO, partM, partL);
  merge_kern<<<dim3(16, 64), 256, 0, stream>>>(valid, perm, partO, partM, partL, ob);
  gemm_bt64<<<dim3(16, 64), 256, 0, stream>>>(ob, wo, out);
}